// Round 2
// baseline (661.051 us; speedup 1.0000x reference)
//
#include <hip/hip_runtime.h>
#include <hip/hip_bf16.h>

#define N_NODES 50000
#define N_EDGES 800000
#define EP (N_EDGES + N_NODES)   // edges incl self loops
#define N_GRAPHS 64
#define F_DIM 128                // = F_IN = H*C
#define OUT_DIM 10

// ---------------- CSR build ----------------

__global__ void hist_kernel(const int* __restrict__ ei, int* __restrict__ deg) {
    int e = blockIdx.x * blockDim.x + threadIdx.x;
    if (e >= EP) return;
    int dst = (e < N_EDGES) ? ei[N_EDGES + e] : (e - N_EDGES);
    atomicAdd(&deg[dst], 1);
}

__global__ __launch_bounds__(1024) void scan_kernel(const int* __restrict__ deg,
                                                    int* __restrict__ rowstart, int n) {
    __shared__ int sdata[1024];
    __shared__ int s_carry;
    int t = threadIdx.x;
    if (t == 0) s_carry = 0;
    __syncthreads();
    const int CH = 4096;  // 4 elems per thread
    for (int base = 0; base < n; base += CH) {
        int v[4];
        int idx0 = base + t * 4;
        int localsum = 0;
        #pragma unroll
        for (int j = 0; j < 4; ++j) {
            int i = idx0 + j;
            v[j] = (i < n) ? deg[i] : 0;
            localsum += v[j];
        }
        sdata[t] = localsum;
        __syncthreads();
        for (int off = 1; off < 1024; off <<= 1) {
            int tmp = (t >= off) ? sdata[t - off] : 0;
            __syncthreads();
            sdata[t] += tmp;
            __syncthreads();
        }
        int excl  = sdata[t] - localsum;
        int total = sdata[1023];
        int carry = s_carry;
        int run = carry + excl;
        #pragma unroll
        for (int j = 0; j < 4; ++j) {
            int i = idx0 + j;
            if (i < n) rowstart[i] = run;
            run += v[j];
        }
        __syncthreads();
        if (t == 0) s_carry = carry + total;
        __syncthreads();
    }
    if (t == 0) rowstart[n] = s_carry;
}

__global__ void fill_kernel(const int* __restrict__ ei, const int* __restrict__ rowstart,
                            int* __restrict__ cursor, int* __restrict__ eids) {
    int e = blockIdx.x * blockDim.x + threadIdx.x;
    if (e >= EP) return;
    int src, dst;
    if (e < N_EDGES) { src = ei[e]; dst = ei[N_EDGES + e]; }
    else             { src = e - N_EDGES; dst = src; }
    int pos = atomicAdd(&cursor[dst], 1);
    eids[rowstart[dst] + pos] = src;
}

// ---------------- per-layer prep ----------------

// ws_eff[f][h] = sum_c Ws[f][h*64+c] * as[h][c]   (collapses xd/xs -> attention scalars)
__global__ void weff_kernel(const float* __restrict__ Ws, const float* __restrict__ as_,
                            const float* __restrict__ Wd, const float* __restrict__ ad_,
                            float* __restrict__ ws_eff, float* __restrict__ wd_eff) {
    int t = threadIdx.x;          // 256 threads
    int f = t >> 1, h = t & 1;
    float ss = 0.f, dd = 0.f;
    for (int c = 0; c < 64; ++c) {
        ss += Ws[f * 128 + h * 64 + c] * as_[h * 64 + c];
        dd += Wd[f * 128 + h * 64 + c] * ad_[h * 64 + c];
    }
    ws_eff[f * 2 + h] = ss;
    wd_eff[f * 2 + h] = dd;
}

// a_s[n][h] = x[n] . ws_eff[:,h] ; a_d likewise
__global__ void avec_kernel(const float* __restrict__ X,
                            const float* __restrict__ ws_eff, const float* __restrict__ wd_eff,
                            float* __restrict__ a_s, float* __restrict__ a_d, int n) {
    int nid = blockIdx.x * blockDim.x + threadIdx.x;
    if (nid >= n) return;
    float s0 = 0, s1 = 0, d0 = 0, d1 = 0;
    const float* xr = X + (size_t)nid * F_DIM;
    for (int f = 0; f < F_DIM; ++f) {
        float xv = xr[f];
        s0 += xv * ws_eff[f * 2 + 0];
        s1 += xv * ws_eff[f * 2 + 1];
        d0 += xv * wd_eff[f * 2 + 0];
        d1 += xv * wd_eff[f * 2 + 1];
    }
    a_s[nid * 2 + 0] = s0; a_s[nid * 2 + 1] = s1;
    a_d[nid * 2 + 0] = d0; a_d[nid * 2 + 1] = d1;
}

// ---------------- GEMM: C[n][128] = A[n][128] @ W[128][128] ----------------

__global__ __launch_bounds__(256) void gemm128_kernel(const float* __restrict__ A,
                                                      const float* __restrict__ W,
                                                      float* __restrict__ C, int n) {
    __shared__ float sX[64][33];   // +1 pad
    __shared__ float sW[32][128];
    int t = threadIdx.x;
    int block_row = blockIdx.x * 64;
    int ty = t >> 5;               // 8 row-groups of 8 rows
    int tx = t & 31;               // 32 col-groups of 4 cols
    float acc[8][4] = {};
    for (int k0 = 0; k0 < 128; k0 += 32) {
        for (int j = t; j < 64 * 32; j += 256) {
            int r = j >> 5, c = j & 31;
            int gr = block_row + r;
            sX[r][c] = (gr < n) ? A[(size_t)gr * 128 + k0 + c] : 0.f;
        }
        for (int j = t; j < 32 * 128; j += 256) {
            int r = j >> 7, c = j & 127;
            sW[r][c] = W[(k0 + r) * 128 + c];
        }
        __syncthreads();
        #pragma unroll
        for (int k = 0; k < 32; ++k) {
            float4 w4 = *(const float4*)&sW[k][tx * 4];
            #pragma unroll
            for (int i = 0; i < 8; ++i) {
                float xv = sX[ty * 8 + i][k];
                acc[i][0] += xv * w4.x;
                acc[i][1] += xv * w4.y;
                acc[i][2] += xv * w4.z;
                acc[i][3] += xv * w4.w;
            }
        }
        __syncthreads();
    }
    for (int i = 0; i < 8; ++i) {
        int gr = block_row + ty * 8 + i;
        if (gr < n) {
            float4 v = make_float4(acc[i][0], acc[i][1], acc[i][2], acc[i][3]);
            *(float4*)&C[(size_t)gr * 128 + tx * 4] = v;
        }
    }
}

// ---------------- edge aggregation: one wave per destination node ----------------

__global__ __launch_bounds__(256) void aggregate_kernel(
    const int* __restrict__ rowstart, const int* __restrict__ eids,
    const float* __restrict__ a_s, const float* __restrict__ a_d,
    const float* __restrict__ xs, const float* __restrict__ bias,
    float* __restrict__ out, int n) {
    int wave = (int)((blockIdx.x * blockDim.x + threadIdx.x) >> 6);
    int lane = threadIdx.x & 63;
    if (wave >= n) return;
    int dstn = wave;
    int h  = lane >> 5;            // head for this lane's channels
    int ch = lane * 2;             // channels ch, ch+1
    float adv = a_d[dstn * 2 + h];
    int row = rowstart[dstn], end = rowstart[dstn + 1];
    float m = -1e30f, l = 0.f, acc0 = 0.f, acc1 = 0.f;
    for (int i = row; i < end; ++i) {
        int srcn = eids[i];
        float e = a_s[srcn * 2 + h] + adv;
        e = (e > 0.f) ? e : 0.2f * e;               // leaky relu
        float2 v = *(const float2*)(xs + (size_t)srcn * 128 + ch);
        float newm  = fmaxf(m, e);
        float scale = __expf(m - newm);
        float p     = __expf(e - newm);
        l    = l * scale + p;
        acc0 = acc0 * scale + p * v.x;
        acc1 = acc1 * scale + p * v.y;
        m = newm;
    }
    float inv = 1.f / l;           // >=1 edge guaranteed (self loop)
    float o0 = acc0 * inv + bias[ch];
    float o1 = acc1 * inv + bias[ch + 1];
    out[(size_t)dstn * 128 + ch]     = fmaxf(o0, 0.f);
    out[(size_t)dstn * 128 + ch + 1] = fmaxf(o1, 0.f);
}

// ---------------- pool (mean by graph) + final linear, fused ----------------

__global__ __launch_bounds__(256) void pool_linear_kernel(
    const float* __restrict__ Hf, const int* __restrict__ batch,
    const float* __restrict__ Wl, const float* __restrict__ bl,
    float* __restrict__ out, int n) {
    __shared__ float part[256];
    __shared__ float pooled[128];
    int g = blockIdx.x;
    int lo = 0, hi = n;
    while (lo < hi) { int mid = (lo + hi) >> 1; if (batch[mid] < g) lo = mid + 1; else hi = mid; }
    int start = lo;
    hi = n;
    while (lo < hi) { int mid = (lo + hi) >> 1; if (batch[mid] < g + 1) lo = mid + 1; else hi = mid; }
    int end = lo;
    int t = threadIdx.x;
    int c = t & 127, half = t >> 7;
    float acc = 0.f;
    for (int i = start + half; i < end; i += 2)
        acc += Hf[(size_t)i * 128 + c];
    part[t] = acc;
    __syncthreads();
    if (t < 128) {
        float cnt = (float)(end - start);
        pooled[t] = (part[t] + part[t + 128]) / fmaxf(cnt, 1.f);
    }
    __syncthreads();
    if (t < OUT_DIM) {
        float s = bl[t];
        for (int c2 = 0; c2 < 128; ++c2) s += pooled[c2] * Wl[c2 * OUT_DIM + t];
        out[g * OUT_DIM + t] = s;
    }
}

// ---------------- launch ----------------

extern "C" void kernel_launch(void* const* d_in, const int* in_sizes, int n_in,
                              void* d_out, int out_size, void* d_ws, size_t ws_size,
                              hipStream_t stream) {
    const float* x    = (const float*)d_in[0];
    const int*   ei   = (const int*)d_in[1];
    const int*   batch= (const int*)d_in[2];
    const float* Ws1  = (const float*)d_in[3];
    const float* Wd1  = (const float*)d_in[4];
    const float* as1  = (const float*)d_in[5];
    const float* ad1  = (const float*)d_in[6];
    const float* b1   = (const float*)d_in[7];
    const float* Ws2  = (const float*)d_in[8];
    const float* Wd2  = (const float*)d_in[9];
    const float* as2  = (const float*)d_in[10];
    const float* ad2  = (const float*)d_in[11];
    const float* b2   = (const float*)d_in[12];
    const float* Wl   = (const float*)d_in[13];
    const float* bl   = (const float*)d_in[14];
    float* out = (float*)d_out;

    // workspace layout (256B aligned slices)
    char* p = (char*)d_ws;
    auto alloc = [&](size_t bytes) {
        void* r = (void*)p;
        p += (bytes + 255) & ~(size_t)255;
        return r;
    };
    // deg+cursor contiguous (single block) so ONE memset covers both exactly.
    int* degcur   = (int*)alloc(sizeof(int) * N_NODES * 2);
    int* deg      = degcur;
    int* cursor   = degcur + N_NODES;
    int* rowstart = (int*)alloc(sizeof(int) * (N_NODES + 1));
    int* eids     = (int*)alloc(sizeof(int) * EP);
    float* a_s    = (float*)alloc(sizeof(float) * N_NODES * 2);
    float* a_d    = (float*)alloc(sizeof(float) * N_NODES * 2);
    float* weff_s = (float*)alloc(sizeof(float) * 128 * 2);
    float* weff_d = (float*)alloc(sizeof(float) * 128 * 2);
    float* bufA   = (float*)alloc(sizeof(float) * (size_t)N_NODES * F_DIM);  // xs
    float* bufB   = (float*)alloc(sizeof(float) * (size_t)N_NODES * F_DIM);  // h

    // ---- CSR build (shared by both layers) ----
    hipMemsetAsync(degcur, 0, sizeof(int) * N_NODES * 2, stream);
    hist_kernel<<<(EP + 255) / 256, 256, 0, stream>>>(ei, deg);
    scan_kernel<<<1, 1024, 0, stream>>>(deg, rowstart, N_NODES);
    fill_kernel<<<(EP + 255) / 256, 256, 0, stream>>>(ei, rowstart, cursor, eids);

    const int gemm_grid = (N_NODES + 63) / 64;
    const int agg_grid  = (N_NODES + 3) / 4;   // 4 waves (dst nodes) per 256-thread block

    // ---- layer 1 ----
    weff_kernel<<<1, 256, 0, stream>>>(Ws1, as1, Wd1, ad1, weff_s, weff_d);
    avec_kernel<<<(N_NODES + 255) / 256, 256, 0, stream>>>(x, weff_s, weff_d, a_s, a_d, N_NODES);
    gemm128_kernel<<<gemm_grid, 256, 0, stream>>>(x, Ws1, bufA, N_NODES);
    aggregate_kernel<<<agg_grid, 256, 0, stream>>>(rowstart, eids, a_s, a_d, bufA, b1, bufB, N_NODES);

    // ---- layer 2 (input bufB, xs2 in bufA, out back to bufB) ----
    weff_kernel<<<1, 256, 0, stream>>>(Ws2, as2, Wd2, ad2, weff_s, weff_d);
    avec_kernel<<<(N_NODES + 255) / 256, 256, 0, stream>>>(bufB, weff_s, weff_d, a_s, a_d, N_NODES);
    gemm128_kernel<<<gemm_grid, 256, 0, stream>>>(bufB, Ws2, bufA, N_NODES);
    aggregate_kernel<<<agg_grid, 256, 0, stream>>>(rowstart, eids, a_s, a_d, bufA, b2, bufB, N_NODES);

    // ---- pool + linear ----
    pool_linear_kernel<<<N_GRAPHS, 256, 0, stream>>>(bufB, batch, Wl, bl, out, N_NODES);
}

// Round 3
// 578.165 us; speedup vs baseline: 1.1434x; 1.1434x over previous
//
#include <hip/hip_runtime.h>
#include <hip/hip_bf16.h>

#define N_NODES 50000
#define N_EDGES 800000
#define EP (N_EDGES + N_NODES)   // edges incl self loops
#define N_GRAPHS 64
#define F_DIM 128                // = F_IN = H*C
#define OUT_DIM 10

// ---------------- CSR build ----------------

__global__ void hist_kernel(const int* __restrict__ ei, int* __restrict__ deg) {
    int e = blockIdx.x * blockDim.x + threadIdx.x;
    if (e >= EP) return;
    int dst = (e < N_EDGES) ? ei[N_EDGES + e] : (e - N_EDGES);
    atomicAdd(&deg[dst], 1);
}

// single-block scan, wave-shuffle based (2 barriers per 4096-chunk)
__global__ __launch_bounds__(1024) void scan_kernel(const int* __restrict__ deg,
                                                    int* __restrict__ rowstart, int n) {
    __shared__ int wsum[16];
    __shared__ int woff[16];
    __shared__ int s_carry;
    int t = threadIdx.x;
    int lane = t & 63, wid = t >> 6;
    if (t == 0) s_carry = 0;
    __syncthreads();
    for (int base = 0; base < n; base += 4096) {
        int idx0 = base + t * 4;
        int v[4];
        int localsum = 0;
        #pragma unroll
        for (int j = 0; j < 4; ++j) {
            int i = idx0 + j;
            v[j] = (i < n) ? deg[i] : 0;
            localsum += v[j];
        }
        int incl = localsum;                    // wave-level inclusive scan
        #pragma unroll
        for (int d = 1; d < 64; d <<= 1) {
            int o = __shfl_up(incl, d, 64);
            if (lane >= d) incl += o;
        }
        if (lane == 63) wsum[wid] = incl;
        __syncthreads();
        if (t == 0) {
            int run = s_carry;
            for (int w = 0; w < 16; ++w) { woff[w] = run; run += wsum[w]; }
            s_carry = run;
        }
        __syncthreads();
        int run = woff[wid] + (incl - localsum);
        #pragma unroll
        for (int j = 0; j < 4; ++j) {
            int i = idx0 + j;
            if (i < n) rowstart[i] = run;
            run += v[j];
        }
    }
    if (t == 0) rowstart[n] = s_carry;
}

__global__ void fill_kernel(const int* __restrict__ ei, const int* __restrict__ rowstart,
                            int* __restrict__ cursor, int* __restrict__ eids) {
    int e = blockIdx.x * blockDim.x + threadIdx.x;
    if (e >= EP) return;
    int src, dst;
    if (e < N_EDGES) { src = ei[e]; dst = ei[N_EDGES + e]; }
    else             { src = e - N_EDGES; dst = src; }
    int pos = atomicAdd(&cursor[dst], 1);
    eids[rowstart[dst] + pos] = src;
}

// ---------------- per-layer prep ----------------

// ws_eff[f][h] = sum_c Ws[f][h*64+c] * as[h][c]   (collapses xd/xs -> attention scalars)
__global__ void weff_kernel(const float* __restrict__ Ws, const float* __restrict__ as_,
                            const float* __restrict__ Wd, const float* __restrict__ ad_,
                            float* __restrict__ ws_eff, float* __restrict__ wd_eff) {
    int t = threadIdx.x;          // 256 threads
    int f = t >> 1, h = t & 1;
    float ss = 0.f, dd = 0.f;
    for (int c = 0; c < 64; ++c) {
        ss += Ws[f * 128 + h * 64 + c] * as_[h * 64 + c];
        dd += Wd[f * 128 + h * 64 + c] * ad_[h * 64 + c];
    }
    ws_eff[f * 2 + h] = ss;
    wd_eff[f * 2 + h] = dd;
}

// a_s[n][h] = x[n] . ws_eff[:,h] ; a_d likewise
__global__ void avec_kernel(const float* __restrict__ X,
                            const float* __restrict__ ws_eff, const float* __restrict__ wd_eff,
                            float* __restrict__ a_s, float* __restrict__ a_d, int n) {
    int nid = blockIdx.x * blockDim.x + threadIdx.x;
    if (nid >= n) return;
    float s0 = 0, s1 = 0, d0 = 0, d1 = 0;
    const float* xr = X + (size_t)nid * F_DIM;
    for (int f = 0; f < F_DIM; ++f) {
        float xv = xr[f];
        s0 += xv * ws_eff[f * 2 + 0];
        s1 += xv * ws_eff[f * 2 + 1];
        d0 += xv * wd_eff[f * 2 + 0];
        d1 += xv * wd_eff[f * 2 + 1];
    }
    a_s[nid * 2 + 0] = s0; a_s[nid * 2 + 1] = s1;
    a_d[nid * 2 + 0] = d0; a_d[nid * 2 + 1] = d1;
}

// ---------------- GEMM: C[n][128] = A[n][128] @ W[128][128] ----------------

__global__ __launch_bounds__(256) void gemm128_kernel(const float* __restrict__ A,
                                                      const float* __restrict__ W,
                                                      float* __restrict__ C, int n) {
    __shared__ float sX[64][33];   // +1 pad
    __shared__ float sW[32][128];
    int t = threadIdx.x;
    int block_row = blockIdx.x * 64;
    int ty = t >> 5;               // 8 row-groups of 8 rows
    int tx = t & 31;               // 32 col-groups of 4 cols
    float acc[8][4] = {};
    for (int k0 = 0; k0 < 128; k0 += 32) {
        for (int j = t; j < 64 * 32; j += 256) {
            int r = j >> 5, c = j & 31;
            int gr = block_row + r;
            sX[r][c] = (gr < n) ? A[(size_t)gr * 128 + k0 + c] : 0.f;
        }
        for (int j = t; j < 32 * 128; j += 256) {
            int r = j >> 7, c = j & 127;
            sW[r][c] = W[(k0 + r) * 128 + c];
        }
        __syncthreads();
        #pragma unroll
        for (int k = 0; k < 32; ++k) {
            float4 w4 = *(const float4*)&sW[k][tx * 4];
            #pragma unroll
            for (int i = 0; i < 8; ++i) {
                float xv = sX[ty * 8 + i][k];
                acc[i][0] += xv * w4.x;
                acc[i][1] += xv * w4.y;
                acc[i][2] += xv * w4.z;
                acc[i][3] += xv * w4.w;
            }
        }
        __syncthreads();
    }
    for (int i = 0; i < 8; ++i) {
        int gr = block_row + ty * 8 + i;
        if (gr < n) {
            float4 v = make_float4(acc[i][0], acc[i][1], acc[i][2], acc[i][3]);
            *(float4*)&C[(size_t)gr * 128 + tx * 4] = v;
        }
    }
}

// ---------------- edge aggregation: one wave per destination node ----------------

__global__ __launch_bounds__(256) void aggregate_kernel(
    const int* __restrict__ rowstart, const int* __restrict__ eids,
    const float* __restrict__ a_s, const float* __restrict__ a_d,
    const float* __restrict__ xs, const float* __restrict__ bias,
    float* __restrict__ out, int n) {
    int wave = (int)((blockIdx.x * blockDim.x + threadIdx.x) >> 6);
    int lane = threadIdx.x & 63;
    if (wave >= n) return;
    int dstn = wave;
    int h  = lane >> 5;            // head for this lane's channels
    int ch = lane * 2;             // channels ch, ch+1
    float adv = a_d[dstn * 2 + h];
    int row = rowstart[dstn], end = rowstart[dstn + 1];
    float m = -1e30f, l = 0.f, acc0 = 0.f, acc1 = 0.f;
    for (int i = row; i < end; ++i) {
        int srcn = eids[i];
        float e = a_s[srcn * 2 + h] + adv;
        e = (e > 0.f) ? e : 0.2f * e;               // leaky relu
        float2 v = *(const float2*)(xs + (size_t)srcn * 128 + ch);
        float newm  = fmaxf(m, e);
        float scale = __expf(m - newm);
        float p     = __expf(e - newm);
        l    = l * scale + p;
        acc0 = acc0 * scale + p * v.x;
        acc1 = acc1 * scale + p * v.y;
        m = newm;
    }
    float inv = 1.f / l;           // >=1 edge guaranteed (self loop)
    float o0 = acc0 * inv + bias[ch];
    float o1 = acc1 * inv + bias[ch + 1];
    out[(size_t)dstn * 128 + ch]     = fmaxf(o0, 0.f);
    out[(size_t)dstn * 128 + ch + 1] = fmaxf(o1, 0.f);
}

// ---------------- pool: partial sums (chunked, coalesced) + tiny final linear ----------------

#define POOL_CHUNK 128

__global__ __launch_bounds__(256) void pool_partial_kernel(
    const float* __restrict__ Hf, const int* __restrict__ batch,
    float* __restrict__ sums, int n) {
    int t = threadIdx.x;
    int c = t & 127, half = t >> 7;
    int start = blockIdx.x * POOL_CHUNK;
    int end = min(start + POOL_CHUNK, n);
    float acc = 0.f;
    int cur = -1;
    for (int i = start + half; i < end; i += 2) {
        int g = batch[i];                           // broadcast load (sorted)
        if (g != cur) {
            if (cur >= 0) atomicAdd(&sums[cur * 128 + c], acc);
            acc = 0.f; cur = g;
        }
        acc += Hf[(size_t)i * 128 + c];
    }
    if (cur >= 0) atomicAdd(&sums[cur * 128 + c], acc);
}

__global__ void final_linear_kernel(const float* __restrict__ sums,
                                    const int* __restrict__ batch,
                                    const float* __restrict__ Wl, const float* __restrict__ bl,
                                    float* __restrict__ out, int n) {
    int t = blockIdx.x * blockDim.x + threadIdx.x;
    if (t >= N_GRAPHS * OUT_DIM) return;
    int g = t / OUT_DIM, o = t % OUT_DIM;
    int lo = 0, hi = n;
    while (lo < hi) { int mid = (lo + hi) >> 1; if (batch[mid] < g) lo = mid + 1; else hi = mid; }
    int s0 = lo; hi = n;
    while (lo < hi) { int mid = (lo + hi) >> 1; if (batch[mid] < g + 1) lo = mid + 1; else hi = mid; }
    float cnt = (float)(lo - s0);
    float inv = 1.f / fmaxf(cnt, 1.f);
    float s = bl[o];
    for (int c = 0; c < 128; ++c) s += sums[g * 128 + c] * inv * Wl[c * OUT_DIM + o];
    out[g * OUT_DIM + o] = s;
}

// ---------------- launch ----------------

extern "C" void kernel_launch(void* const* d_in, const int* in_sizes, int n_in,
                              void* d_out, int out_size, void* d_ws, size_t ws_size,
                              hipStream_t stream) {
    const float* x    = (const float*)d_in[0];
    const int*   ei   = (const int*)d_in[1];
    const int*   batch= (const int*)d_in[2];
    const float* Ws1  = (const float*)d_in[3];
    const float* Wd1  = (const float*)d_in[4];
    const float* as1  = (const float*)d_in[5];
    const float* ad1  = (const float*)d_in[6];
    const float* b1   = (const float*)d_in[7];
    const float* Ws2  = (const float*)d_in[8];
    const float* Wd2  = (const float*)d_in[9];
    const float* as2  = (const float*)d_in[10];
    const float* ad2  = (const float*)d_in[11];
    const float* b2   = (const float*)d_in[12];
    const float* Wl   = (const float*)d_in[13];
    const float* bl   = (const float*)d_in[14];
    float* out = (float*)d_out;

    // workspace layout (256B aligned slices)
    char* p = (char*)d_ws;
    auto alloc = [&](size_t bytes) {
        void* r = (void*)p;
        p += (bytes + 255) & ~(size_t)255;
        return r;
    };
    // deg+cursor contiguous (single block) so ONE memset covers both exactly.
    int* degcur   = (int*)alloc(sizeof(int) * N_NODES * 2);
    int* deg      = degcur;
    int* cursor   = degcur + N_NODES;
    int* rowstart = (int*)alloc(sizeof(int) * (N_NODES + 1));
    int* eids     = (int*)alloc(sizeof(int) * EP);
    float* a_s    = (float*)alloc(sizeof(float) * N_NODES * 2);
    float* a_d    = (float*)alloc(sizeof(float) * N_NODES * 2);
    float* weff_s = (float*)alloc(sizeof(float) * 128 * 2);
    float* weff_d = (float*)alloc(sizeof(float) * 128 * 2);
    float* sums   = (float*)alloc(sizeof(float) * N_GRAPHS * 128);
    float* bufA   = (float*)alloc(sizeof(float) * (size_t)N_NODES * F_DIM);  // xs
    float* bufB   = (float*)alloc(sizeof(float) * (size_t)N_NODES * F_DIM);  // h

    // ---- CSR build (shared by both layers) ----
    hipMemsetAsync(degcur, 0, sizeof(int) * N_NODES * 2, stream);
    hipMemsetAsync(sums, 0, sizeof(float) * N_GRAPHS * 128, stream);
    hist_kernel<<<(EP + 255) / 256, 256, 0, stream>>>(ei, deg);
    scan_kernel<<<1, 1024, 0, stream>>>(deg, rowstart, N_NODES);
    fill_kernel<<<(EP + 255) / 256, 256, 0, stream>>>(ei, rowstart, cursor, eids);

    const int gemm_grid = (N_NODES + 63) / 64;
    const int agg_grid  = (N_NODES + 3) / 4;   // 4 waves (dst nodes) per 256-thread block

    // ---- layer 1 ----
    weff_kernel<<<1, 256, 0, stream>>>(Ws1, as1, Wd1, ad1, weff_s, weff_d);
    avec_kernel<<<(N_NODES + 255) / 256, 256, 0, stream>>>(x, weff_s, weff_d, a_s, a_d, N_NODES);
    gemm128_kernel<<<gemm_grid, 256, 0, stream>>>(x, Ws1, bufA, N_NODES);
    aggregate_kernel<<<agg_grid, 256, 0, stream>>>(rowstart, eids, a_s, a_d, bufA, b1, bufB, N_NODES);

    // ---- layer 2 (input bufB, xs2 in bufA, out back to bufB) ----
    weff_kernel<<<1, 256, 0, stream>>>(Ws2, as2, Wd2, ad2, weff_s, weff_d);
    avec_kernel<<<(N_NODES + 255) / 256, 256, 0, stream>>>(bufB, weff_s, weff_d, a_s, a_d, N_NODES);
    gemm128_kernel<<<gemm_grid, 256, 0, stream>>>(bufB, Ws2, bufA, N_NODES);
    aggregate_kernel<<<agg_grid, 256, 0, stream>>>(rowstart, eids, a_s, a_d, bufA, b2, bufB, N_NODES);

    // ---- pool + linear ----
    pool_partial_kernel<<<(N_NODES + POOL_CHUNK - 1) / POOL_CHUNK, 256, 0, stream>>>(bufB, batch, sums, N_NODES);
    final_linear_kernel<<<(N_GRAPHS * OUT_DIM + 255) / 256, 256, 0, stream>>>(sums, batch, Wl, bl, out, N_NODES);
}

// Round 4
// 507.938 us; speedup vs baseline: 1.3014x; 1.1383x over previous
//
#include <hip/hip_runtime.h>
#include <hip/hip_bf16.h>

#define N_NODES 50000
#define N_EDGES 800000
#define EP (N_EDGES + N_NODES)   // edges incl self loops
#define N_GRAPHS 64
#define F_DIM 128                // = F_IN = H*C
#define OUT_DIM 10

typedef __attribute__((ext_vector_type(8))) short short8;   // 8 bf16 (4 VGPRs)
typedef __attribute__((ext_vector_type(4))) float f32x4;

__device__ __forceinline__ float bf2f(unsigned int u16) {
    unsigned int x = u16 << 16;
    float f; __builtin_memcpy(&f, &x, 4); return f;
}
__device__ __forceinline__ unsigned int f2bf(float f) {
    unsigned int x; __builtin_memcpy(&x, &f, 4);
    return (x + 0x7fffu + ((x >> 16) & 1u)) >> 16;          // RNE
}

// ---------------- CSR build ----------------

__global__ void hist_kernel(const int* __restrict__ ei, int* __restrict__ deg) {
    int e = blockIdx.x * blockDim.x + threadIdx.x;
    if (e >= EP) return;
    int dst = (e < N_EDGES) ? ei[N_EDGES + e] : (e - N_EDGES);
    atomicAdd(&deg[dst], 1);
}

// single-block scan, wave-shuffle based
__global__ __launch_bounds__(1024) void scan_kernel(const int* __restrict__ deg,
                                                    int* __restrict__ rowstart, int n) {
    __shared__ int wsum[16];
    __shared__ int woff[16];
    __shared__ int s_carry;
    int t = threadIdx.x;
    int lane = t & 63, wid = t >> 6;
    if (t == 0) s_carry = 0;
    __syncthreads();
    for (int base = 0; base < n; base += 4096) {
        int idx0 = base + t * 4;
        int v[4];
        int localsum = 0;
        #pragma unroll
        for (int j = 0; j < 4; ++j) {
            int i = idx0 + j;
            v[j] = (i < n) ? deg[i] : 0;
            localsum += v[j];
        }
        int incl = localsum;
        #pragma unroll
        for (int d = 1; d < 64; d <<= 1) {
            int o = __shfl_up(incl, d, 64);
            if (lane >= d) incl += o;
        }
        if (lane == 63) wsum[wid] = incl;
        __syncthreads();
        if (t == 0) {
            int run = s_carry;
            for (int w = 0; w < 16; ++w) { woff[w] = run; run += wsum[w]; }
            s_carry = run;
        }
        __syncthreads();
        int run = woff[wid] + (incl - localsum);
        #pragma unroll
        for (int j = 0; j < 4; ++j) {
            int i = idx0 + j;
            if (i < n) rowstart[i] = run;
            run += v[j];
        }
    }
    if (t == 0) rowstart[n] = s_carry;
}

__global__ void fill_kernel(const int* __restrict__ ei, const int* __restrict__ rowstart,
                            int* __restrict__ cursor, int* __restrict__ eids) {
    int e = blockIdx.x * blockDim.x + threadIdx.x;
    if (e >= EP) return;
    int src, dst;
    if (e < N_EDGES) { src = ei[e]; dst = ei[N_EDGES + e]; }
    else             { src = e - N_EDGES; dst = src; }
    int pos = atomicAdd(&cursor[dst], 1);
    eids[rowstart[dst] + pos] = src;
}

// ---------------- casts ----------------

// f32 -> bf16, 4 elems/thread
__global__ void cast_x_kernel(const float* __restrict__ x, unsigned short* __restrict__ xb) {
    int idx = (blockIdx.x * blockDim.x + threadIdx.x) * 4;   // total divisible by 4
    float4 v = *(const float4*)(x + idx);
    unsigned int lo = f2bf(v.x) | (f2bf(v.y) << 16);
    unsigned int hi = f2bf(v.z) | (f2bf(v.w) << 16);
    *(uint2*)(xb + idx) = make_uint2(lo, hi);
}

// W[128][128] (k,n) -> Wt[n][k] bf16 (transposed for MFMA B-fragment contiguity)
__global__ void castT_w_kernel(const float* __restrict__ W, unsigned short* __restrict__ Wt) {
    int idx = blockIdx.x * blockDim.x + threadIdx.x;   // 16384 threads
    int k = idx >> 7, n = idx & 127;
    Wt[n * 128 + k] = (unsigned short)f2bf(W[idx]);
}

// ---------------- per-layer prep ----------------

// ws_eff[f][h] = sum_c Ws[f][h*64+c] * as[h][c]
__global__ void weff_kernel(const float* __restrict__ Ws, const float* __restrict__ as_,
                            const float* __restrict__ Wd, const float* __restrict__ ad_,
                            float* __restrict__ ws_eff, float* __restrict__ wd_eff) {
    int t = threadIdx.x;          // 256 threads
    int f = t >> 1, h = t & 1;
    float ss = 0.f, dd = 0.f;
    for (int c = 0; c < 64; ++c) {
        ss += Ws[f * 128 + h * 64 + c] * as_[h * 64 + c];
        dd += Wd[f * 128 + h * 64 + c] * ad_[h * 64 + c];
    }
    ws_eff[f * 2 + h] = ss;
    wd_eff[f * 2 + h] = dd;
}

// a_s/a_d from f32 X (layer 1)
__global__ void avec_kernel(const float* __restrict__ X,
                            const float* __restrict__ ws_eff, const float* __restrict__ wd_eff,
                            float* __restrict__ a_s, float* __restrict__ a_d, int n) {
    int nid = blockIdx.x * blockDim.x + threadIdx.x;
    if (nid >= n) return;
    float s0 = 0, s1 = 0, d0 = 0, d1 = 0;
    const float* xr = X + (size_t)nid * F_DIM;
    for (int f = 0; f < F_DIM; ++f) {
        float xv = xr[f];
        s0 += xv * ws_eff[f * 2 + 0];
        s1 += xv * ws_eff[f * 2 + 1];
        d0 += xv * wd_eff[f * 2 + 0];
        d1 += xv * wd_eff[f * 2 + 1];
    }
    a_s[nid * 2 + 0] = s0; a_s[nid * 2 + 1] = s1;
    a_d[nid * 2 + 0] = d0; a_d[nid * 2 + 1] = d1;
}

// a_s/a_d from bf16 X (layer 2)
__global__ void avec_bf16_kernel(const unsigned int* __restrict__ X32,
                                 const float* __restrict__ ws_eff, const float* __restrict__ wd_eff,
                                 float* __restrict__ a_s, float* __restrict__ a_d, int n) {
    int nid = blockIdx.x * blockDim.x + threadIdx.x;
    if (nid >= n) return;
    float s0 = 0, s1 = 0, d0 = 0, d1 = 0;
    const unsigned int* xr = X32 + (size_t)nid * 64;
    for (int f2 = 0; f2 < 64; ++f2) {
        unsigned int v = xr[f2];
        float x0 = bf2f(v & 0xffffu), x1 = bf2f(v >> 16);
        int f0 = 2 * f2, f1 = 2 * f2 + 1;
        s0 += x0 * ws_eff[f0 * 2 + 0] + x1 * ws_eff[f1 * 2 + 0];
        s1 += x0 * ws_eff[f0 * 2 + 1] + x1 * ws_eff[f1 * 2 + 1];
        d0 += x0 * wd_eff[f0 * 2 + 0] + x1 * wd_eff[f1 * 2 + 0];
        d1 += x0 * wd_eff[f0 * 2 + 1] + x1 * wd_eff[f1 * 2 + 1];
    }
    a_s[nid * 2 + 0] = s0; a_s[nid * 2 + 1] = s1;
    a_d[nid * 2 + 0] = d0; a_d[nid * 2 + 1] = d1;
}

// ---------------- MFMA GEMM: C[n][128] = A[n][128] @ W[128][128], all bf16 ----------------
// A row-major bf16; Wt = W^T row-major bf16 ([nout][kin]).
// 16x16x32 MFMA: A-frag lane l holds A[m0 + (l&15)][kb*32 + (l>>4)*8 + j], j=0..7 (16B contig)
//                B-frag lane l holds W[kb*32 + (l>>4)*8 + j][n0 + (l&15)] = Wt[n0+(l&15)][...] (16B contig)
//                D lane l reg r -> row m0 + (l>>4)*4 + r, col n0 + (l&15)
__global__ __launch_bounds__(256) void gemm_mfma_kernel(const unsigned short* __restrict__ A,
                                                        const unsigned short* __restrict__ Wt,
                                                        unsigned short* __restrict__ C, int n) {
    int t = threadIdx.x;
    int w = t >> 6, l = t & 63;
    int quad = l >> 4, lr = l & 15;
    int m0 = blockIdx.x * 64 + w * 16;
    int arow = m0 + lr; if (arow >= n) arow = n - 1;   // clamp loads; stores guarded

    short8 afrag[4];
    #pragma unroll
    for (int kb = 0; kb < 4; ++kb)
        afrag[kb] = *(const short8*)(A + (size_t)arow * 128 + kb * 32 + quad * 8);

    f32x4 acc[8] = {};
    #pragma unroll
    for (int nt = 0; nt < 8; ++nt) {
        #pragma unroll
        for (int kb = 0; kb < 4; ++kb) {
            short8 b = *(const short8*)(Wt + (size_t)(nt * 16 + lr) * 128 + kb * 32 + quad * 8);
            acc[nt] = __builtin_amdgcn_mfma_f32_16x16x32_bf16(afrag[kb], b, acc[nt], 0, 0, 0);
        }
    }
    #pragma unroll
    for (int nt = 0; nt < 8; ++nt) {
        #pragma unroll
        for (int r = 0; r < 4; ++r) {
            int row = m0 + quad * 4 + r;
            if (row < n)
                C[(size_t)row * 128 + nt * 16 + lr] = (unsigned short)f2bf(acc[nt][r]);
        }
    }
}

// ---------------- edge aggregation: one wave per destination node (bf16 features) ----------------

__global__ __launch_bounds__(256) void aggregate_kernel(
    const int* __restrict__ rowstart, const int* __restrict__ eids,
    const float* __restrict__ a_s, const float* __restrict__ a_d,
    const unsigned int* __restrict__ xs32, const float* __restrict__ bias,
    unsigned int* __restrict__ out32, int n) {
    int wave = (int)((blockIdx.x * blockDim.x + threadIdx.x) >> 6);
    int lane = threadIdx.x & 63;
    if (wave >= n) return;
    int dstn = wave;
    int h  = lane >> 5;            // head for this lane's channels
    int ch = lane * 2;             // channels ch, ch+1
    float adv = a_d[dstn * 2 + h];
    int row = rowstart[dstn], end = rowstart[dstn + 1];
    float m = -1e30f, l = 0.f, acc0 = 0.f, acc1 = 0.f;
    for (int i = row; i < end; ++i) {
        int srcn = eids[i];
        float e = a_s[srcn * 2 + h] + adv;
        e = (e > 0.f) ? e : 0.2f * e;               // leaky relu
        unsigned int v = xs32[(size_t)srcn * 64 + lane];
        float v0 = bf2f(v & 0xffffu), v1 = bf2f(v >> 16);
        float newm  = fmaxf(m, e);
        float scale = __expf(m - newm);
        float p     = __expf(e - newm);
        l    = l * scale + p;
        acc0 = acc0 * scale + p * v0;
        acc1 = acc1 * scale + p * v1;
        m = newm;
    }
    float inv = 1.f / l;           // >=1 edge guaranteed (self loop)
    float o0 = fmaxf(acc0 * inv + bias[ch], 0.f);      // + bias, relu
    float o1 = fmaxf(acc1 * inv + bias[ch + 1], 0.f);
    out32[(size_t)dstn * 64 + lane] = f2bf(o0) | (f2bf(o1) << 16);
}

// ---------------- pool: partial sums (chunked, coalesced) + tiny final linear ----------------

#define POOL_CHUNK 128

__global__ __launch_bounds__(256) void pool_partial_kernel(
    const unsigned short* __restrict__ Hf, const int* __restrict__ batch,
    float* __restrict__ sums, int n) {
    int t = threadIdx.x;
    int c = t & 127, half = t >> 7;
    int start = blockIdx.x * POOL_CHUNK;
    int end = min(start + POOL_CHUNK, n);
    float acc = 0.f;
    int cur = -1;
    for (int i = start + half; i < end; i += 2) {
        int g = batch[i];                           // broadcast load (sorted)
        if (g != cur) {
            if (cur >= 0) atomicAdd(&sums[cur * 128 + c], acc);
            acc = 0.f; cur = g;
        }
        acc += bf2f(Hf[(size_t)i * 128 + c]);
    }
    if (cur >= 0) atomicAdd(&sums[cur * 128 + c], acc);
}

__global__ void final_linear_kernel(const float* __restrict__ sums,
                                    const int* __restrict__ batch,
                                    const float* __restrict__ Wl, const float* __restrict__ bl,
                                    float* __restrict__ out, int n) {
    int t = blockIdx.x * blockDim.x + threadIdx.x;
    if (t >= N_GRAPHS * OUT_DIM) return;
    int g = t / OUT_DIM, o = t % OUT_DIM;
    int lo = 0, hi = n;
    while (lo < hi) { int mid = (lo + hi) >> 1; if (batch[mid] < g) lo = mid + 1; else hi = mid; }
    int s0 = lo; hi = n;
    while (lo < hi) { int mid = (lo + hi) >> 1; if (batch[mid] < g + 1) lo = mid + 1; else hi = mid; }
    float cnt = (float)(lo - s0);
    float inv = 1.f / fmaxf(cnt, 1.f);
    float s = bl[o];
    for (int c = 0; c < 128; ++c) s += sums[g * 128 + c] * inv * Wl[c * OUT_DIM + o];
    out[g * OUT_DIM + o] = s;
}

// ---------------- launch ----------------

extern "C" void kernel_launch(void* const* d_in, const int* in_sizes, int n_in,
                              void* d_out, int out_size, void* d_ws, size_t ws_size,
                              hipStream_t stream) {
    const float* x    = (const float*)d_in[0];
    const int*   ei   = (const int*)d_in[1];
    const int*   batch= (const int*)d_in[2];
    const float* Ws1  = (const float*)d_in[3];
    const float* Wd1  = (const float*)d_in[4];
    const float* as1  = (const float*)d_in[5];
    const float* ad1  = (const float*)d_in[6];
    const float* b1   = (const float*)d_in[7];
    const float* Ws2  = (const float*)d_in[8];
    const float* Wd2  = (const float*)d_in[9];
    const float* as2  = (const float*)d_in[10];
    const float* ad2  = (const float*)d_in[11];
    const float* b2   = (const float*)d_in[12];
    const float* Wl   = (const float*)d_in[13];
    const float* bl   = (const float*)d_in[14];
    float* out = (float*)d_out;

    // workspace layout (256B aligned slices)
    char* p = (char*)d_ws;
    auto alloc = [&](size_t bytes) {
        void* r = (void*)p;
        p += (bytes + 255) & ~(size_t)255;
        return r;
    };
    int* degcur   = (int*)alloc(sizeof(int) * N_NODES * 2);   // deg+cursor contiguous: one memset
    int* deg      = degcur;
    int* cursor   = degcur + N_NODES;
    int* rowstart = (int*)alloc(sizeof(int) * (N_NODES + 1));
    int* eids     = (int*)alloc(sizeof(int) * EP);
    float* a_s    = (float*)alloc(sizeof(float) * N_NODES * 2);
    float* a_d    = (float*)alloc(sizeof(float) * N_NODES * 2);
    float* weff_s = (float*)alloc(sizeof(float) * 128 * 2);
    float* weff_d = (float*)alloc(sizeof(float) * 128 * 2);
    float* sums   = (float*)alloc(sizeof(float) * N_GRAPHS * 128);
    unsigned short* xb   = (unsigned short*)alloc(sizeof(short) * (size_t)N_NODES * F_DIM);
    unsigned short* Wt1  = (unsigned short*)alloc(sizeof(short) * 128 * 128);
    unsigned short* Wt2  = (unsigned short*)alloc(sizeof(short) * 128 * 128);
    unsigned short* bufA = (unsigned short*)alloc(sizeof(short) * (size_t)N_NODES * F_DIM); // xs
    unsigned short* bufB = (unsigned short*)alloc(sizeof(short) * (size_t)N_NODES * F_DIM); // h

    // ---- CSR build (shared by both layers) + casts ----
    hipMemsetAsync(degcur, 0, sizeof(int) * N_NODES * 2, stream);
    hipMemsetAsync(sums, 0, sizeof(float) * N_GRAPHS * 128, stream);
    hist_kernel<<<(EP + 255) / 256, 256, 0, stream>>>(ei, deg);
    scan_kernel<<<1, 1024, 0, stream>>>(deg, rowstart, N_NODES);
    fill_kernel<<<(EP + 255) / 256, 256, 0, stream>>>(ei, rowstart, cursor, eids);
    cast_x_kernel<<<(N_NODES * F_DIM / 4) / 256, 256, 0, stream>>>(x, xb);
    castT_w_kernel<<<64, 256, 0, stream>>>(Ws1, Wt1);
    castT_w_kernel<<<64, 256, 0, stream>>>(Ws2, Wt2);

    const int gemm_grid = (N_NODES + 63) / 64;
    const int agg_grid  = (N_NODES + 3) / 4;   // 4 waves (dst nodes) per 256-thread block

    // ---- layer 1 ----
    weff_kernel<<<1, 256, 0, stream>>>(Ws1, as1, Wd1, ad1, weff_s, weff_d);
    avec_kernel<<<(N_NODES + 255) / 256, 256, 0, stream>>>(x, weff_s, weff_d, a_s, a_d, N_NODES);
    gemm_mfma_kernel<<<gemm_grid, 256, 0, stream>>>(xb, Wt1, bufA, N_NODES);
    aggregate_kernel<<<agg_grid, 256, 0, stream>>>(rowstart, eids, a_s, a_d,
                                                   (const unsigned int*)bufA, b1,
                                                   (unsigned int*)bufB, N_NODES);

    // ---- layer 2 ----
    weff_kernel<<<1, 256, 0, stream>>>(Ws2, as2, Wd2, ad2, weff_s, weff_d);
    avec_bf16_kernel<<<(N_NODES + 255) / 256, 256, 0, stream>>>((const unsigned int*)bufB,
                                                                weff_s, weff_d, a_s, a_d, N_NODES);
    gemm_mfma_kernel<<<gemm_grid, 256, 0, stream>>>(bufB, Wt2, bufA, N_NODES);
    aggregate_kernel<<<agg_grid, 256, 0, stream>>>(rowstart, eids, a_s, a_d,
                                                   (const unsigned int*)bufA, b2,
                                                   (unsigned int*)bufB, N_NODES);

    // ---- pool + linear ----
    pool_partial_kernel<<<(N_NODES + POOL_CHUNK - 1) / POOL_CHUNK, 256, 0, stream>>>(bufB, batch, sums, N_NODES);
    final_linear_kernel<<<(N_GRAPHS * OUT_DIM + 255) / 256, 256, 0, stream>>>(sums, batch, Wl, bl, out, N_NODES);
}

// Round 5
// 438.734 us; speedup vs baseline: 1.5067x; 1.1577x over previous
//
#include <hip/hip_runtime.h>
#include <hip/hip_bf16.h>

#define N_NODES 50000
#define N_EDGES 800000
#define EP (N_EDGES + N_NODES)   // edges incl self loops
#define N_GRAPHS 64
#define F_DIM 128                // = F_IN = H*C
#define OUT_DIM 10

typedef __attribute__((ext_vector_type(8))) short short8;   // 8 bf16 (4 VGPRs)
typedef __attribute__((ext_vector_type(4))) float f32x4;

__device__ __forceinline__ float bf2f(unsigned int u16) {
    unsigned int x = u16 << 16;
    float f; __builtin_memcpy(&f, &x, 4); return f;
}
__device__ __forceinline__ unsigned int f2bf(float f) {
    unsigned int x; __builtin_memcpy(&x, &f, 4);
    return (x + 0x7fffu + ((x >> 16) & 1u)) >> 16;          // RNE
}

// ---------------- CSR build ----------------

__global__ void hist_kernel(const int* __restrict__ ei, int* __restrict__ deg) {
    int e = blockIdx.x * blockDim.x + threadIdx.x;
    if (e >= EP) return;
    int dst = (e < N_EDGES) ? ei[N_EDGES + e] : (e - N_EDGES);
    atomicAdd(&deg[dst], 1);
}

// single-block scan, wave-shuffle based
__global__ __launch_bounds__(1024) void scan_kernel(const int* __restrict__ deg,
                                                    int* __restrict__ rowstart, int n) {
    __shared__ int wsum[16];
    __shared__ int woff[16];
    __shared__ int s_carry;
    int t = threadIdx.x;
    int lane = t & 63, wid = t >> 6;
    if (t == 0) s_carry = 0;
    __syncthreads();
    for (int base = 0; base < n; base += 4096) {
        int idx0 = base + t * 4;
        int v[4];
        int localsum = 0;
        #pragma unroll
        for (int j = 0; j < 4; ++j) {
            int i = idx0 + j;
            v[j] = (i < n) ? deg[i] : 0;
            localsum += v[j];
        }
        int incl = localsum;
        #pragma unroll
        for (int d = 1; d < 64; d <<= 1) {
            int o = __shfl_up(incl, d, 64);
            if (lane >= d) incl += o;
        }
        if (lane == 63) wsum[wid] = incl;
        __syncthreads();
        if (t == 0) {
            int run = s_carry;
            for (int w = 0; w < 16; ++w) { woff[w] = run; run += wsum[w]; }
            s_carry = run;
        }
        __syncthreads();
        int run = woff[wid] + (incl - localsum);
        #pragma unroll
        for (int j = 0; j < 4; ++j) {
            int i = idx0 + j;
            if (i < n) rowstart[i] = run;
            run += v[j];
        }
    }
    if (t == 0) rowstart[n] = s_carry;
}

__global__ void fill_kernel(const int* __restrict__ ei, const int* __restrict__ rowstart,
                            int* __restrict__ cursor, int* __restrict__ eids) {
    int e = blockIdx.x * blockDim.x + threadIdx.x;
    if (e >= EP) return;
    int src, dst;
    if (e < N_EDGES) { src = ei[e]; dst = ei[N_EDGES + e]; }
    else             { src = e - N_EDGES; dst = src; }
    int pos = atomicAdd(&cursor[dst], 1);
    eids[rowstart[dst] + pos] = src;
}

// ---------------- casts ----------------

__global__ void cast_x_kernel(const float* __restrict__ x, unsigned short* __restrict__ xb) {
    int idx = (blockIdx.x * blockDim.x + threadIdx.x) * 4;
    float4 v = *(const float4*)(x + idx);
    unsigned int lo = f2bf(v.x) | (f2bf(v.y) << 16);
    unsigned int hi = f2bf(v.z) | (f2bf(v.w) << 16);
    *(uint2*)(xb + idx) = make_uint2(lo, hi);
}

// W[128][128] (k,n) -> Wt[n][k] bf16
__global__ void castT_w_kernel(const float* __restrict__ W, unsigned short* __restrict__ Wt) {
    int idx = blockIdx.x * blockDim.x + threadIdx.x;
    int k = idx >> 7, n = idx & 127;
    Wt[n * 128 + k] = (unsigned short)f2bf(W[idx]);
}

// ---------------- fused weff + avec (attention scalar projections) ----------------
// Block computes ws_eff/wd_eff into LDS (redundantly per block), then 1 node/thread.

__global__ __launch_bounds__(256) void avec_f32_kernel(
    const float* __restrict__ X,
    const float* __restrict__ Ws, const float* __restrict__ as_,
    const float* __restrict__ Wd, const float* __restrict__ ad_,
    float* __restrict__ a_s, float* __restrict__ a_d, int n) {
    __shared__ float sS[256], sD[256];          // [f*2+h]
    int t = threadIdx.x;
    {
        int f = t >> 1, h = t & 1;
        const float4* wsr = (const float4*)(Ws + f * 128 + h * 64);
        const float4* wdr = (const float4*)(Wd + f * 128 + h * 64);
        const float4* av  = (const float4*)(as_ + h * 64);
        const float4* bv  = (const float4*)(ad_ + h * 64);
        float ss = 0.f, dd = 0.f;
        #pragma unroll
        for (int c = 0; c < 16; ++c) {
            float4 w1 = wsr[c], a1 = av[c], w2 = wdr[c], a2 = bv[c];
            ss += w1.x*a1.x + w1.y*a1.y + w1.z*a1.z + w1.w*a1.w;
            dd += w2.x*a2.x + w2.y*a2.y + w2.z*a2.z + w2.w*a2.w;
        }
        sS[f * 2 + h] = ss; sD[f * 2 + h] = dd;
    }
    __syncthreads();
    int nid = blockIdx.x * 256 + t;
    if (nid >= n) return;
    const float4* xr = (const float4*)(X + (size_t)nid * 128);
    float s0 = 0, s1 = 0, d0 = 0, d1 = 0;
    #pragma unroll
    for (int q = 0; q < 32; ++q) {
        float4 xv = xr[q];
        int f8 = q * 8;
        s0 += xv.x*sS[f8+0] + xv.y*sS[f8+2] + xv.z*sS[f8+4] + xv.w*sS[f8+6];
        s1 += xv.x*sS[f8+1] + xv.y*sS[f8+3] + xv.z*sS[f8+5] + xv.w*sS[f8+7];
        d0 += xv.x*sD[f8+0] + xv.y*sD[f8+2] + xv.z*sD[f8+4] + xv.w*sD[f8+6];
        d1 += xv.x*sD[f8+1] + xv.y*sD[f8+3] + xv.z*sD[f8+5] + xv.w*sD[f8+7];
    }
    a_s[nid * 2 + 0] = s0; a_s[nid * 2 + 1] = s1;
    a_d[nid * 2 + 0] = d0; a_d[nid * 2 + 1] = d1;
}

__global__ __launch_bounds__(256) void avec_bf16_kernel(
    const unsigned int* __restrict__ X32,
    const float* __restrict__ Ws, const float* __restrict__ as_,
    const float* __restrict__ Wd, const float* __restrict__ ad_,
    float* __restrict__ a_s, float* __restrict__ a_d, int n) {
    __shared__ float sS[256], sD[256];
    int t = threadIdx.x;
    {
        int f = t >> 1, h = t & 1;
        const float4* wsr = (const float4*)(Ws + f * 128 + h * 64);
        const float4* wdr = (const float4*)(Wd + f * 128 + h * 64);
        const float4* av  = (const float4*)(as_ + h * 64);
        const float4* bv  = (const float4*)(ad_ + h * 64);
        float ss = 0.f, dd = 0.f;
        #pragma unroll
        for (int c = 0; c < 16; ++c) {
            float4 w1 = wsr[c], a1 = av[c], w2 = wdr[c], a2 = bv[c];
            ss += w1.x*a1.x + w1.y*a1.y + w1.z*a1.z + w1.w*a1.w;
            dd += w2.x*a2.x + w2.y*a2.y + w2.z*a2.z + w2.w*a2.w;
        }
        sS[f * 2 + h] = ss; sD[f * 2 + h] = dd;
    }
    __syncthreads();
    int nid = blockIdx.x * 256 + t;
    if (nid >= n) return;
    const uint2* xr = (const uint2*)(X32 + (size_t)nid * 64);
    float s0 = 0, s1 = 0, d0 = 0, d1 = 0;
    #pragma unroll
    for (int q = 0; q < 32; ++q) {
        uint2 u = xr[q];
        float x0 = bf2f(u.x & 0xffffu), x1 = bf2f(u.x >> 16);
        float x2 = bf2f(u.y & 0xffffu), x3 = bf2f(u.y >> 16);
        int f8 = q * 8;
        s0 += x0*sS[f8+0] + x1*sS[f8+2] + x2*sS[f8+4] + x3*sS[f8+6];
        s1 += x0*sS[f8+1] + x1*sS[f8+3] + x2*sS[f8+5] + x3*sS[f8+7];
        d0 += x0*sD[f8+0] + x1*sD[f8+2] + x2*sD[f8+4] + x3*sD[f8+6];
        d1 += x0*sD[f8+1] + x1*sD[f8+3] + x2*sD[f8+5] + x3*sD[f8+7];
    }
    a_s[nid * 2 + 0] = s0; a_s[nid * 2 + 1] = s1;
    a_d[nid * 2 + 0] = d0; a_d[nid * 2 + 1] = d1;
}

// ---------------- MFMA GEMM: C[n][128] = A[n][128] @ W[128][128], all bf16 ----------------

__global__ __launch_bounds__(256) void gemm_mfma_kernel(const unsigned short* __restrict__ A,
                                                        const unsigned short* __restrict__ Wt,
                                                        unsigned short* __restrict__ C, int n) {
    int t = threadIdx.x;
    int w = t >> 6, l = t & 63;
    int quad = l >> 4, lr = l & 15;
    int m0 = blockIdx.x * 64 + w * 16;
    int arow = m0 + lr; if (arow >= n) arow = n - 1;

    short8 afrag[4];
    #pragma unroll
    for (int kb = 0; kb < 4; ++kb)
        afrag[kb] = *(const short8*)(A + (size_t)arow * 128 + kb * 32 + quad * 8);

    f32x4 acc[8] = {};
    #pragma unroll
    for (int nt = 0; nt < 8; ++nt) {
        #pragma unroll
        for (int kb = 0; kb < 4; ++kb) {
            short8 b = *(const short8*)(Wt + (size_t)(nt * 16 + lr) * 128 + kb * 32 + quad * 8);
            acc[nt] = __builtin_amdgcn_mfma_f32_16x16x32_bf16(afrag[kb], b, acc[nt], 0, 0, 0);
        }
    }
    #pragma unroll
    for (int nt = 0; nt < 8; ++nt) {
        #pragma unroll
        for (int r = 0; r < 4; ++r) {
            int row = m0 + quad * 4 + r;
            if (row < n)
                C[(size_t)row * 128 + nt * 16 + lr] = (unsigned short)f2bf(acc[nt][r]);
        }
    }
}

// ---------------- edge aggregation: one wave per destination node ----------------
// Unstabilized softmax (exact in f32 for this data range): alpha = exp(e)/sum(exp(e)).
// Per 64-edge chunk, lane j loads edge j's src + a_s and computes BOTH heads' exp
// in parallel; the inner per-edge loop is then readlane + gather + 2 FMA.

__global__ __launch_bounds__(256) void aggregate_kernel(
    const int* __restrict__ rowstart, const int* __restrict__ eids,
    const float* __restrict__ a_s, const float* __restrict__ a_d,
    const unsigned int* __restrict__ xs32, const float* __restrict__ bias,
    unsigned int* __restrict__ out32, int n) {
    int wave = (int)((blockIdx.x * blockDim.x + threadIdx.x) >> 6);
    int lane = threadIdx.x & 63;
    if (wave >= n) return;
    int dstn = wave;
    int h  = lane >> 5;
    int ch = lane * 2;
    float adv0 = a_d[dstn * 2 + 0];
    float adv1 = a_d[dstn * 2 + 1];
    int row = rowstart[dstn], end = rowstart[dstn + 1];

    float acc0 = 0.f, acc1 = 0.f, lsum0 = 0.f, lsum1 = 0.f;
    for (int base = row; base < end; base += 64) {
        int rem = end - base;                       // >= 1
        int k = rem < 64 ? rem : 64;
        int idx = base + (lane < k ? lane : k - 1); // clamp (safe addr)
        int my_eid = eids[idx];
        float2 as2 = *(const float2*)(a_s + (size_t)my_eid * 2);
        float e0 = as2.x + adv0; e0 = (e0 > 0.f) ? e0 : 0.2f * e0;
        float e1 = as2.y + adv1; e1 = (e1 > 0.f) ? e1 : 0.2f * e1;
        float p0 = (lane < k) ? __expf(e0) : 0.f;
        float p1 = (lane < k) ? __expf(e1) : 0.f;
        lsum0 += p0; lsum1 += p1;
        for (int j = 0; j < k; ++j) {
            int srcn  = __shfl(my_eid, j);
            float pj0 = __shfl(p0, j);
            float pj1 = __shfl(p1, j);
            float pj  = (h == 0) ? pj0 : pj1;
            unsigned int v = xs32[(size_t)srcn * 64 + lane];
            float v0 = __uint_as_float(v << 16);
            float v1 = __uint_as_float(v & 0xffff0000u);
            acc0 += pj * v0;
            acc1 += pj * v1;
        }
    }
    // wave-wide denominators
    #pragma unroll
    for (int d = 32; d > 0; d >>= 1) {
        lsum0 += __shfl_xor(lsum0, d);
        lsum1 += __shfl_xor(lsum1, d);
    }
    float inv = 1.f / ((h == 0) ? lsum0 : lsum1);
    float o0 = fmaxf(acc0 * inv + bias[ch], 0.f);
    float o1 = fmaxf(acc1 * inv + bias[ch + 1], 0.f);
    out32[(size_t)dstn * 64 + lane] = f2bf(o0) | (f2bf(o1) << 16);
}

// ---------------- pool: partial sums + tiny final linear ----------------

#define POOL_CHUNK 128

__global__ __launch_bounds__(256) void pool_partial_kernel(
    const unsigned short* __restrict__ Hf, const int* __restrict__ batch,
    float* __restrict__ sums, int n) {
    int t = threadIdx.x;
    int c = t & 127, half = t >> 7;
    int start = blockIdx.x * POOL_CHUNK;
    int end = min(start + POOL_CHUNK, n);
    float acc = 0.f;
    int cur = -1;
    for (int i = start + half; i < end; i += 2) {
        int g = batch[i];
        if (g != cur) {
            if (cur >= 0) atomicAdd(&sums[cur * 128 + c], acc);
            acc = 0.f; cur = g;
        }
        acc += bf2f(Hf[(size_t)i * 128 + c]);
    }
    if (cur >= 0) atomicAdd(&sums[cur * 128 + c], acc);
}

__global__ void final_linear_kernel(const float* __restrict__ sums,
                                    const int* __restrict__ batch,
                                    const float* __restrict__ Wl, const float* __restrict__ bl,
                                    float* __restrict__ out, int n) {
    int t = blockIdx.x * blockDim.x + threadIdx.x;
    if (t >= N_GRAPHS * OUT_DIM) return;
    int g = t / OUT_DIM, o = t % OUT_DIM;
    int lo = 0, hi = n;
    while (lo < hi) { int mid = (lo + hi) >> 1; if (batch[mid] < g) lo = mid + 1; else hi = mid; }
    int s0 = lo; hi = n;
    while (lo < hi) { int mid = (lo + hi) >> 1; if (batch[mid] < g + 1) lo = mid + 1; else hi = mid; }
    float cnt = (float)(lo - s0);
    float inv = 1.f / fmaxf(cnt, 1.f);
    float s = bl[o];
    for (int c = 0; c < 128; ++c) s += sums[g * 128 + c] * inv * Wl[c * OUT_DIM + o];
    out[g * OUT_DIM + o] = s;
}

// ---------------- launch ----------------

extern "C" void kernel_launch(void* const* d_in, const int* in_sizes, int n_in,
                              void* d_out, int out_size, void* d_ws, size_t ws_size,
                              hipStream_t stream) {
    const float* x    = (const float*)d_in[0];
    const int*   ei   = (const int*)d_in[1];
    const int*   batch= (const int*)d_in[2];
    const float* Ws1  = (const float*)d_in[3];
    const float* Wd1  = (const float*)d_in[4];
    const float* as1  = (const float*)d_in[5];
    const float* ad1  = (const float*)d_in[6];
    const float* b1   = (const float*)d_in[7];
    const float* Ws2  = (const float*)d_in[8];
    const float* Wd2  = (const float*)d_in[9];
    const float* as2  = (const float*)d_in[10];
    const float* ad2  = (const float*)d_in[11];
    const float* b2   = (const float*)d_in[12];
    const float* Wl   = (const float*)d_in[13];
    const float* bl   = (const float*)d_in[14];
    float* out = (float*)d_out;

    char* p = (char*)d_ws;
    auto alloc = [&](size_t bytes) {
        void* r = (void*)p;
        p += (bytes + 255) & ~(size_t)255;
        return r;
    };
    int* degcur   = (int*)alloc(sizeof(int) * N_NODES * 2);   // deg+cursor: one memset
    int* deg      = degcur;
    int* cursor   = degcur + N_NODES;
    int* rowstart = (int*)alloc(sizeof(int) * (N_NODES + 1));
    int* eids     = (int*)alloc(sizeof(int) * EP);
    float* a_s    = (float*)alloc(sizeof(float) * N_NODES * 2);
    float* a_d    = (float*)alloc(sizeof(float) * N_NODES * 2);
    float* sums   = (float*)alloc(sizeof(float) * N_GRAPHS * 128);
    unsigned short* xb   = (unsigned short*)alloc(sizeof(short) * (size_t)N_NODES * F_DIM);
    unsigned short* Wt1  = (unsigned short*)alloc(sizeof(short) * 128 * 128);
    unsigned short* Wt2  = (unsigned short*)alloc(sizeof(short) * 128 * 128);
    unsigned short* bufA = (unsigned short*)alloc(sizeof(short) * (size_t)N_NODES * F_DIM); // xs
    unsigned short* bufB = (unsigned short*)alloc(sizeof(short) * (size_t)N_NODES * F_DIM); // h

    // ---- CSR build + casts ----
    hipMemsetAsync(degcur, 0, sizeof(int) * N_NODES * 2, stream);
    hipMemsetAsync(sums, 0, sizeof(float) * N_GRAPHS * 128, stream);
    hist_kernel<<<(EP + 255) / 256, 256, 0, stream>>>(ei, deg);
    scan_kernel<<<1, 1024, 0, stream>>>(deg, rowstart, N_NODES);
    fill_kernel<<<(EP + 255) / 256, 256, 0, stream>>>(ei, rowstart, cursor, eids);
    cast_x_kernel<<<(N_NODES * F_DIM / 4) / 256, 256, 0, stream>>>(x, xb);
    castT_w_kernel<<<64, 256, 0, stream>>>(Ws1, Wt1);
    castT_w_kernel<<<64, 256, 0, stream>>>(Ws2, Wt2);

    const int gemm_grid = (N_NODES + 63) / 64;
    const int agg_grid  = (N_NODES + 3) / 4;
    const int avec_grid = (N_NODES + 255) / 256;

    // ---- layer 1 ----
    avec_f32_kernel<<<avec_grid, 256, 0, stream>>>(x, Ws1, as1, Wd1, ad1, a_s, a_d, N_NODES);
    gemm_mfma_kernel<<<gemm_grid, 256, 0, stream>>>(xb, Wt1, bufA, N_NODES);
    aggregate_kernel<<<agg_grid, 256, 0, stream>>>(rowstart, eids, a_s, a_d,
                                                   (const unsigned int*)bufA, b1,
                                                   (unsigned int*)bufB, N_NODES);

    // ---- layer 2 ----
    avec_bf16_kernel<<<avec_grid, 256, 0, stream>>>((const unsigned int*)bufB,
                                                    Ws2, as2, Wd2, ad2, a_s, a_d, N_NODES);
    gemm_mfma_kernel<<<gemm_grid, 256, 0, stream>>>(bufB, Wt2, bufA, N_NODES);
    aggregate_kernel<<<agg_grid, 256, 0, stream>>>(rowstart, eids, a_s, a_d,
                                                   (const unsigned int*)bufA, b2,
                                                   (unsigned int*)bufB, N_NODES);

    // ---- pool + linear ----
    pool_partial_kernel<<<(N_NODES + POOL_CHUNK - 1) / POOL_CHUNK, 256, 0, stream>>>(bufB, batch, sums, N_NODES);
    final_linear_kernel<<<(N_GRAPHS * OUT_DIM + 255) / 256, 256, 0, stream>>>(sums, batch, Wl, bl, out, N_NODES);
}

// Round 6
// 412.513 us; speedup vs baseline: 1.6025x; 1.0636x over previous
//
#include <hip/hip_runtime.h>
#include <hip/hip_bf16.h>

#define N_NODES 50000
#define N_EDGES 800000
#define EP (N_EDGES + N_NODES)   // edges incl self loops
#define N_GRAPHS 64
#define F_DIM 128                // = F_IN = H*C
#define OUT_DIM 10
#define SCAN_BLOCKS 49           // ceil(50000/1024)

typedef __attribute__((ext_vector_type(8))) short short8;   // 8 bf16 (4 VGPRs)
typedef __attribute__((ext_vector_type(4))) float f32x4;

__device__ __forceinline__ float bf2f(unsigned int u16) {
    unsigned int x = u16 << 16;
    float f; __builtin_memcpy(&f, &x, 4); return f;
}
__device__ __forceinline__ unsigned int f2bf(float f) {
    unsigned int x; __builtin_memcpy(&x, &f, 4);
    return (x + 0x7fffu + ((x >> 16) & 1u)) >> 16;          // RNE
}

// ---------------- fused prep: zero deg/cursor/sums + cast both W -> Wt ----------------
// grid = 128 blocks x 256 = 32768 threads

__global__ __launch_bounds__(256) void prep_kernel(
    const float* __restrict__ W1, const float* __restrict__ W2,
    unsigned short* __restrict__ Wt1, unsigned short* __restrict__ Wt2,
    uint4* __restrict__ zero_degcur /*25000*/, uint4* __restrict__ zero_sums /*2048*/) {
    int tid = blockIdx.x * 256 + threadIdx.x;
    if (tid < 25000) zero_degcur[tid] = make_uint4(0, 0, 0, 0);
    else if (tid < 27048) zero_sums[tid - 25000] = make_uint4(0, 0, 0, 0);
    // W cast + transpose: W[k][n] -> Wt[n][k]
    const float* W = (tid < 16384) ? W1 : W2;
    unsigned short* Wt = (tid < 16384) ? Wt1 : Wt2;
    int i = tid & 16383;
    int k = i >> 7, nn = i & 127;
    Wt[nn * 128 + k] = (unsigned short)f2bf(W[i]);
}

// ---------------- CSR build ----------------

__global__ void hist_kernel(const int* __restrict__ ei, int* __restrict__ deg) {
    int e = blockIdx.x * blockDim.x + threadIdx.x;
    if (e >= EP) return;
    int dst = (e < N_EDGES) ? ei[N_EDGES + e] : (e - N_EDGES);
    atomicAdd(&deg[dst], 1);
}

// 3-kernel parallel exclusive scan of deg -> rowstart
__global__ __launch_bounds__(256) void scan_a_kernel(const int* __restrict__ deg,
                                                     int* __restrict__ blocksum, int n) {
    __shared__ int ws[4];
    int t = threadIdx.x;
    int base = blockIdx.x * 1024 + t * 4;
    int s = 0;
    #pragma unroll
    for (int j = 0; j < 4; ++j) { int i = base + j; s += (i < n) ? deg[i] : 0; }
    #pragma unroll
    for (int d = 32; d > 0; d >>= 1) s += __shfl_xor(s, d);
    int lane = t & 63, wid = t >> 6;
    if (lane == 0) ws[wid] = s;
    __syncthreads();
    if (t == 0) blocksum[blockIdx.x] = ws[0] + ws[1] + ws[2] + ws[3];
}

__global__ void scan_b_kernel(const int* __restrict__ blocksum,
                              int* __restrict__ blockoff, int* __restrict__ rowstart, int n) {
    int t = threadIdx.x;   // 64 threads
    int v = (t < SCAN_BLOCKS) ? blocksum[t] : 0;
    int incl = v;
    #pragma unroll
    for (int d = 1; d < 64; d <<= 1) { int o = __shfl_up(incl, d, 64); if (t >= d) incl += o; }
    if (t < SCAN_BLOCKS) blockoff[t] = incl - v;
    if (t == 0) rowstart[n] = EP;
}

__global__ __launch_bounds__(256) void scan_c_kernel(const int* __restrict__ deg,
                                                     const int* __restrict__ blockoff,
                                                     int* __restrict__ rowstart, int n) {
    __shared__ int woff[4];
    int t = threadIdx.x;
    int lane = t & 63, wid = t >> 6;
    int base = blockIdx.x * 1024 + t * 4;
    int v[4]; int ls = 0;
    #pragma unroll
    for (int j = 0; j < 4; ++j) { int i = base + j; v[j] = (i < n) ? deg[i] : 0; ls += v[j]; }
    int incl = ls;
    #pragma unroll
    for (int d = 1; d < 64; d <<= 1) { int o = __shfl_up(incl, d, 64); if (lane >= d) incl += o; }
    if (lane == 63) woff[wid] = incl;
    __syncthreads();
    int wpre = 0;
    for (int w = 0; w < wid; ++w) wpre += woff[w];
    int run = blockoff[blockIdx.x] + wpre + (incl - ls);
    #pragma unroll
    for (int j = 0; j < 4; ++j) { int i = base + j; if (i < n) rowstart[i] = run; run += v[j]; }
}

__global__ void fill_kernel(const int* __restrict__ ei, const int* __restrict__ rowstart,
                            int* __restrict__ cursor, int* __restrict__ eids) {
    int e = blockIdx.x * blockDim.x + threadIdx.x;
    if (e >= EP) return;
    int src, dst;
    if (e < N_EDGES) { src = ei[e]; dst = ei[N_EDGES + e]; }
    else             { src = e - N_EDGES; dst = src; }
    int pos = atomicAdd(&cursor[dst], 1);
    eids[rowstart[dst] + pos] = src;
}

// ---------------- fused weff + avec (attention scalar projections) ----------------

__global__ __launch_bounds__(256) void avec_f32_kernel(
    const float* __restrict__ X,
    const float* __restrict__ Ws, const float* __restrict__ as_,
    const float* __restrict__ Wd, const float* __restrict__ ad_,
    float* __restrict__ a_s, float* __restrict__ a_d, int n) {
    __shared__ float sS[256], sD[256];          // [f*2+h]
    int t = threadIdx.x;
    {
        int f = t >> 1, h = t & 1;
        const float4* wsr = (const float4*)(Ws + f * 128 + h * 64);
        const float4* wdr = (const float4*)(Wd + f * 128 + h * 64);
        const float4* av  = (const float4*)(as_ + h * 64);
        const float4* bv  = (const float4*)(ad_ + h * 64);
        float ss = 0.f, dd = 0.f;
        #pragma unroll
        for (int c = 0; c < 16; ++c) {
            float4 w1 = wsr[c], a1 = av[c], w2 = wdr[c], a2 = bv[c];
            ss += w1.x*a1.x + w1.y*a1.y + w1.z*a1.z + w1.w*a1.w;
            dd += w2.x*a2.x + w2.y*a2.y + w2.z*a2.z + w2.w*a2.w;
        }
        sS[f * 2 + h] = ss; sD[f * 2 + h] = dd;
    }
    __syncthreads();
    int nid = blockIdx.x * 256 + t;
    if (nid >= n) return;
    const float4* xr = (const float4*)(X + (size_t)nid * 128);
    float s0 = 0, s1 = 0, d0 = 0, d1 = 0;
    #pragma unroll
    for (int q = 0; q < 32; ++q) {
        float4 xv = xr[q];
        int f8 = q * 8;
        s0 += xv.x*sS[f8+0] + xv.y*sS[f8+2] + xv.z*sS[f8+4] + xv.w*sS[f8+6];
        s1 += xv.x*sS[f8+1] + xv.y*sS[f8+3] + xv.z*sS[f8+5] + xv.w*sS[f8+7];
        d0 += xv.x*sD[f8+0] + xv.y*sD[f8+2] + xv.z*sD[f8+4] + xv.w*sD[f8+6];
        d1 += xv.x*sD[f8+1] + xv.y*sD[f8+3] + xv.z*sD[f8+5] + xv.w*sD[f8+7];
    }
    a_s[nid * 2 + 0] = s0; a_s[nid * 2 + 1] = s1;
    a_d[nid * 2 + 0] = d0; a_d[nid * 2 + 1] = d1;
}

__global__ __launch_bounds__(256) void avec_bf16_kernel(
    const unsigned int* __restrict__ X32,
    const float* __restrict__ Ws, const float* __restrict__ as_,
    const float* __restrict__ Wd, const float* __restrict__ ad_,
    float* __restrict__ a_s, float* __restrict__ a_d, int n) {
    __shared__ float sS[256], sD[256];
    int t = threadIdx.x;
    {
        int f = t >> 1, h = t & 1;
        const float4* wsr = (const float4*)(Ws + f * 128 + h * 64);
        const float4* wdr = (const float4*)(Wd + f * 128 + h * 64);
        const float4* av  = (const float4*)(as_ + h * 64);
        const float4* bv  = (const float4*)(ad_ + h * 64);
        float ss = 0.f, dd = 0.f;
        #pragma unroll
        for (int c = 0; c < 16; ++c) {
            float4 w1 = wsr[c], a1 = av[c], w2 = wdr[c], a2 = bv[c];
            ss += w1.x*a1.x + w1.y*a1.y + w1.z*a1.z + w1.w*a1.w;
            dd += w2.x*a2.x + w2.y*a2.y + w2.z*a2.z + w2.w*a2.w;
        }
        sS[f * 2 + h] = ss; sD[f * 2 + h] = dd;
    }
    __syncthreads();
    int nid = blockIdx.x * 256 + t;
    if (nid >= n) return;
    const uint2* xr = (const uint2*)(X32 + (size_t)nid * 64);
    float s0 = 0, s1 = 0, d0 = 0, d1 = 0;
    #pragma unroll
    for (int q = 0; q < 32; ++q) {
        uint2 u = xr[q];
        float x0 = bf2f(u.x & 0xffffu), x1 = bf2f(u.x >> 16);
        float x2 = bf2f(u.y & 0xffffu), x3 = bf2f(u.y >> 16);
        int f8 = q * 8;
        s0 += x0*sS[f8+0] + x1*sS[f8+2] + x2*sS[f8+4] + x3*sS[f8+6];
        s1 += x0*sS[f8+1] + x1*sS[f8+3] + x2*sS[f8+5] + x3*sS[f8+7];
        d0 += x0*sD[f8+0] + x1*sD[f8+2] + x2*sD[f8+4] + x3*sD[f8+6];
        d1 += x0*sD[f8+1] + x1*sD[f8+3] + x2*sD[f8+5] + x3*sD[f8+7];
    }
    a_s[nid * 2 + 0] = s0; a_s[nid * 2 + 1] = s1;
    a_d[nid * 2 + 0] = d0; a_d[nid * 2 + 1] = d1;
}

// ---------------- MFMA GEMM: C[n][128] = A[n][128] @ W[128][128] ----------------
// variant 1: A is f32 (layer 1), converted to bf16 fragments in-register

__global__ __launch_bounds__(256) void gemm_mfma_f32a_kernel(const float* __restrict__ A,
                                                             const unsigned short* __restrict__ Wt,
                                                             unsigned short* __restrict__ C, int n) {
    int t = threadIdx.x;
    int w = t >> 6, l = t & 63;
    int quad = l >> 4, lr = l & 15;
    int m0 = blockIdx.x * 64 + w * 16;
    int arow = m0 + lr; if (arow >= n) arow = n - 1;

    short8 afrag[4];
    #pragma unroll
    for (int kb = 0; kb < 4; ++kb) {
        const float4* ap = (const float4*)(A + (size_t)arow * 128 + kb * 32 + quad * 8);
        float4 a0 = ap[0], a1 = ap[1];
        short8 s;
        s[0] = (short)f2bf(a0.x); s[1] = (short)f2bf(a0.y);
        s[2] = (short)f2bf(a0.z); s[3] = (short)f2bf(a0.w);
        s[4] = (short)f2bf(a1.x); s[5] = (short)f2bf(a1.y);
        s[6] = (short)f2bf(a1.z); s[7] = (short)f2bf(a1.w);
        afrag[kb] = s;
    }

    f32x4 acc[8] = {};
    #pragma unroll
    for (int nt = 0; nt < 8; ++nt) {
        #pragma unroll
        for (int kb = 0; kb < 4; ++kb) {
            short8 b = *(const short8*)(Wt + (size_t)(nt * 16 + lr) * 128 + kb * 32 + quad * 8);
            acc[nt] = __builtin_amdgcn_mfma_f32_16x16x32_bf16(afrag[kb], b, acc[nt], 0, 0, 0);
        }
    }
    #pragma unroll
    for (int nt = 0; nt < 8; ++nt) {
        #pragma unroll
        for (int r = 0; r < 4; ++r) {
            int row = m0 + quad * 4 + r;
            if (row < n)
                C[(size_t)row * 128 + nt * 16 + lr] = (unsigned short)f2bf(acc[nt][r]);
        }
    }
}

// variant 2: A is bf16 (layer 2)
__global__ __launch_bounds__(256) void gemm_mfma_kernel(const unsigned short* __restrict__ A,
                                                        const unsigned short* __restrict__ Wt,
                                                        unsigned short* __restrict__ C, int n) {
    int t = threadIdx.x;
    int w = t >> 6, l = t & 63;
    int quad = l >> 4, lr = l & 15;
    int m0 = blockIdx.x * 64 + w * 16;
    int arow = m0 + lr; if (arow >= n) arow = n - 1;

    short8 afrag[4];
    #pragma unroll
    for (int kb = 0; kb < 4; ++kb)
        afrag[kb] = *(const short8*)(A + (size_t)arow * 128 + kb * 32 + quad * 8);

    f32x4 acc[8] = {};
    #pragma unroll
    for (int nt = 0; nt < 8; ++nt) {
        #pragma unroll
        for (int kb = 0; kb < 4; ++kb) {
            short8 b = *(const short8*)(Wt + (size_t)(nt * 16 + lr) * 128 + kb * 32 + quad * 8);
            acc[nt] = __builtin_amdgcn_mfma_f32_16x16x32_bf16(afrag[kb], b, acc[nt], 0, 0, 0);
        }
    }
    #pragma unroll
    for (int nt = 0; nt < 8; ++nt) {
        #pragma unroll
        for (int r = 0; r < 4; ++r) {
            int row = m0 + quad * 4 + r;
            if (row < n)
                C[(size_t)row * 128 + nt * 16 + lr] = (unsigned short)f2bf(acc[nt][r]);
        }
    }
}

// ---------------- edge aggregation: one wave per destination node ----------------
// Unstabilized softmax (exact in f32 for this data range).

__global__ __launch_bounds__(256) void aggregate_kernel(
    const int* __restrict__ rowstart, const int* __restrict__ eids,
    const float* __restrict__ a_s, const float* __restrict__ a_d,
    const unsigned int* __restrict__ xs32, const float* __restrict__ bias,
    unsigned int* __restrict__ out32, int n) {
    int wave = (int)((blockIdx.x * blockDim.x + threadIdx.x) >> 6);
    int lane = threadIdx.x & 63;
    if (wave >= n) return;
    int dstn = wave;
    int h  = lane >> 5;
    int ch = lane * 2;
    float adv0 = a_d[dstn * 2 + 0];
    float adv1 = a_d[dstn * 2 + 1];
    int row = rowstart[dstn], end = rowstart[dstn + 1];

    float acc0 = 0.f, acc1 = 0.f, lsum0 = 0.f, lsum1 = 0.f;
    for (int base = row; base < end; base += 64) {
        int rem = end - base;                       // >= 1
        int k = rem < 64 ? rem : 64;
        int idx = base + (lane < k ? lane : k - 1); // clamp (safe addr)
        int my_eid = eids[idx];
        float2 as2 = *(const float2*)(a_s + (size_t)my_eid * 2);
        float e0 = as2.x + adv0; e0 = (e0 > 0.f) ? e0 : 0.2f * e0;
        float e1 = as2.y + adv1; e1 = (e1 > 0.f) ? e1 : 0.2f * e1;
        float p0 = (lane < k) ? __expf(e0) : 0.f;
        float p1 = (lane < k) ? __expf(e1) : 0.f;
        lsum0 += p0; lsum1 += p1;
        for (int j = 0; j < k; ++j) {
            int srcn  = __shfl(my_eid, j);
            float pj0 = __shfl(p0, j);
            float pj1 = __shfl(p1, j);
            float pj  = (h == 0) ? pj0 : pj1;
            unsigned int v = xs32[(size_t)srcn * 64 + lane];
            float v0 = __uint_as_float(v << 16);
            float v1 = __uint_as_float(v & 0xffff0000u);
            acc0 += pj * v0;
            acc1 += pj * v1;
        }
    }
    #pragma unroll
    for (int d = 32; d > 0; d >>= 1) {
        lsum0 += __shfl_xor(lsum0, d);
        lsum1 += __shfl_xor(lsum1, d);
    }
    float inv = 1.f / ((h == 0) ? lsum0 : lsum1);
    float o0 = fmaxf(acc0 * inv + bias[ch], 0.f);
    float o1 = fmaxf(acc1 * inv + bias[ch + 1], 0.f);
    out32[(size_t)dstn * 64 + lane] = f2bf(o0) | (f2bf(o1) << 16);
}

// ---------------- pool: partial sums + tiny final linear ----------------

#define POOL_CHUNK 128

__global__ __launch_bounds__(256) void pool_partial_kernel(
    const unsigned short* __restrict__ Hf, const int* __restrict__ batch,
    float* __restrict__ sums, int n) {
    int t = threadIdx.x;
    int c = t & 127, half = t >> 7;
    int start = blockIdx.x * POOL_CHUNK;
    int end = min(start + POOL_CHUNK, n);
    float acc = 0.f;
    int cur = -1;
    for (int i = start + half; i < end; i += 2) {
        int g = batch[i];
        if (g != cur) {
            if (cur >= 0) atomicAdd(&sums[cur * 128 + c], acc);
            acc = 0.f; cur = g;
        }
        acc += bf2f(Hf[(size_t)i * 128 + c]);
    }
    if (cur >= 0) atomicAdd(&sums[cur * 128 + c], acc);
}

__global__ void final_linear_kernel(const float* __restrict__ sums,
                                    const int* __restrict__ batch,
                                    const float* __restrict__ Wl, const float* __restrict__ bl,
                                    float* __restrict__ out, int n) {
    int t = blockIdx.x * blockDim.x + threadIdx.x;
    if (t >= N_GRAPHS * OUT_DIM) return;
    int g = t / OUT_DIM, o = t % OUT_DIM;
    int lo = 0, hi = n;
    while (lo < hi) { int mid = (lo + hi) >> 1; if (batch[mid] < g) lo = mid + 1; else hi = mid; }
    int s0 = lo; hi = n;
    while (lo < hi) { int mid = (lo + hi) >> 1; if (batch[mid] < g + 1) lo = mid + 1; else hi = mid; }
    float cnt = (float)(lo - s0);
    float inv = 1.f / fmaxf(cnt, 1.f);
    float s = bl[o];
    for (int c = 0; c < 128; ++c) s += sums[g * 128 + c] * inv * Wl[c * OUT_DIM + o];
    out[g * OUT_DIM + o] = s;
}

// ---------------- launch ----------------

extern "C" void kernel_launch(void* const* d_in, const int* in_sizes, int n_in,
                              void* d_out, int out_size, void* d_ws, size_t ws_size,
                              hipStream_t stream) {
    const float* x    = (const float*)d_in[0];
    const int*   ei   = (const int*)d_in[1];
    const int*   batch= (const int*)d_in[2];
    const float* Ws1  = (const float*)d_in[3];
    const float* Wd1  = (const float*)d_in[4];
    const float* as1  = (const float*)d_in[5];
    const float* ad1  = (const float*)d_in[6];
    const float* b1   = (const float*)d_in[7];
    const float* Ws2  = (const float*)d_in[8];
    const float* Wd2  = (const float*)d_in[9];
    const float* as2  = (const float*)d_in[10];
    const float* ad2  = (const float*)d_in[11];
    const float* b2   = (const float*)d_in[12];
    const float* Wl   = (const float*)d_in[13];
    const float* bl   = (const float*)d_in[14];
    float* out = (float*)d_out;

    char* p = (char*)d_ws;
    auto alloc = [&](size_t bytes) {
        void* r = (void*)p;
        p += (bytes + 255) & ~(size_t)255;
        return r;
    };
    int* degcur   = (int*)alloc(sizeof(int) * N_NODES * 2);   // deg+cursor contiguous
    int* deg      = degcur;
    int* cursor   = degcur + N_NODES;
    int* rowstart = (int*)alloc(sizeof(int) * (N_NODES + 1));
    int* eids     = (int*)alloc(sizeof(int) * EP);
    int* bsum     = (int*)alloc(sizeof(int) * 64);
    int* boff     = (int*)alloc(sizeof(int) * 64);
    float* a_s    = (float*)alloc(sizeof(float) * N_NODES * 2);
    float* a_d    = (float*)alloc(sizeof(float) * N_NODES * 2);
    float* sums   = (float*)alloc(sizeof(float) * N_GRAPHS * 128);
    unsigned short* Wt1  = (unsigned short*)alloc(sizeof(short) * 128 * 128);
    unsigned short* Wt2  = (unsigned short*)alloc(sizeof(short) * 128 * 128);
    unsigned short* bufA = (unsigned short*)alloc(sizeof(short) * (size_t)N_NODES * F_DIM); // xs
    unsigned short* bufB = (unsigned short*)alloc(sizeof(short) * (size_t)N_NODES * F_DIM); // h

    // ---- prep (zeros + W casts) + CSR build ----
    prep_kernel<<<128, 256, 0, stream>>>(Ws1, Ws2, Wt1, Wt2, (uint4*)degcur, (uint4*)sums);
    hist_kernel<<<(EP + 255) / 256, 256, 0, stream>>>(ei, deg);
    scan_a_kernel<<<SCAN_BLOCKS, 256, 0, stream>>>(deg, bsum, N_NODES);
    scan_b_kernel<<<1, 64, 0, stream>>>(bsum, boff, rowstart, N_NODES);
    scan_c_kernel<<<SCAN_BLOCKS, 256, 0, stream>>>(deg, boff, rowstart, N_NODES);
    fill_kernel<<<(EP + 255) / 256, 256, 0, stream>>>(ei, rowstart, cursor, eids);

    const int gemm_grid = (N_NODES + 63) / 64;
    const int agg_grid  = (N_NODES + 3) / 4;
    const int avec_grid = (N_NODES + 255) / 256;

    // ---- layer 1 ----
    avec_f32_kernel<<<avec_grid, 256, 0, stream>>>(x, Ws1, as1, Wd1, ad1, a_s, a_d, N_NODES);
    gemm_mfma_f32a_kernel<<<gemm_grid, 256, 0, stream>>>(x, Wt1, bufA, N_NODES);
    aggregate_kernel<<<agg_grid, 256, 0, stream>>>(rowstart, eids, a_s, a_d,
                                                   (const unsigned int*)bufA, b1,
                                                   (unsigned int*)bufB, N_NODES);

    // ---- layer 2 ----
    avec_bf16_kernel<<<avec_grid, 256, 0, stream>>>((const unsigned int*)bufB,
                                                    Ws2, as2, Wd2, ad2, a_s, a_d, N_NODES);
    gemm_mfma_kernel<<<gemm_grid, 256, 0, stream>>>(bufB, Wt2, bufA, N_NODES);
    aggregate_kernel<<<agg_grid, 256, 0, stream>>>(rowstart, eids, a_s, a_d,
                                                   (const unsigned int*)bufA, b2,
                                                   (unsigned int*)bufB, N_NODES);

    // ---- pool + linear ----
    pool_partial_kernel<<<(N_NODES + POOL_CHUNK - 1) / POOL_CHUNK, 256, 0, stream>>>(bufB, batch, sums, N_NODES);
    final_linear_kernel<<<(N_GRAPHS * OUT_DIM + 255) / 256, 256, 0, stream>>>(sums, batch, Wl, bl, out, N_NODES);
}

// Round 7
// 341.590 us; speedup vs baseline: 1.9352x; 1.2076x over previous
//
#include <hip/hip_runtime.h>
#include <hip/hip_bf16.h>

#define N_NODES 50000
#define N_EDGES 800000
#define EP (N_EDGES + N_NODES)   // edges incl self loops
#define N_GRAPHS 64
#define F_DIM 128                // = F_IN = H*C
#define OUT_DIM 10
#define SCAN_BLOCKS 49           // ceil(50000/1024)

typedef __attribute__((ext_vector_type(8))) short short8;   // 8 bf16 (4 VGPRs)
typedef __attribute__((ext_vector_type(4))) float f32x4;

__device__ __forceinline__ float bf2f(unsigned int u16) {
    unsigned int x = u16 << 16;
    float f; __builtin_memcpy(&f, &x, 4); return f;
}
__device__ __forceinline__ unsigned int f2bf(float f) {
    unsigned int x; __builtin_memcpy(&x, &f, 4);
    return (x + 0x7fffu + ((x >> 16) & 1u)) >> 16;          // RNE
}

// ---------------- prep: zeros + W->Wt casts + weff_d (Wd·ad collapse) ----------------
// grid = 128 blocks x 256

__global__ __launch_bounds__(256) void prep_kernel(
    const float* __restrict__ W1, const float* __restrict__ W2,
    const float* __restrict__ Wd1, const float* __restrict__ ad1,
    const float* __restrict__ Wd2, const float* __restrict__ ad2,
    unsigned short* __restrict__ Wt1, unsigned short* __restrict__ Wt2,
    float* __restrict__ weffd1, float* __restrict__ weffd2,
    uint4* __restrict__ zero_degcur /*25000*/, uint4* __restrict__ zero_sums /*2048*/) {
    int tid = blockIdx.x * 256 + threadIdx.x;
    if (tid < 25000) zero_degcur[tid] = make_uint4(0, 0, 0, 0);
    else if (tid < 27048) zero_sums[tid - 25000] = make_uint4(0, 0, 0, 0);
    // weff_d for both layers: weffd[f*2+h] = sum_c Wd[f*128+h*64+c]*ad[h*64+c]
    if (tid < 512) {
        const float* Wd = (tid < 256) ? Wd1 : Wd2;
        const float* ad = (tid < 256) ? ad1 : ad2;
        float* wout = (tid < 256) ? weffd1 : weffd2;
        int i = tid & 255, f = i >> 1, h = i & 1;
        const float4* wr = (const float4*)(Wd + f * 128 + h * 64);
        const float4* av = (const float4*)(ad + h * 64);
        float s = 0.f;
        #pragma unroll
        for (int c = 0; c < 16; ++c) {
            float4 w = wr[c], a = av[c];
            s += w.x*a.x + w.y*a.y + w.z*a.z + w.w*a.w;
        }
        wout[f * 2 + h] = s;
    }
    // W cast + transpose: W[k][n] -> Wt[n][k]
    const float* W = (tid < 16384) ? W1 : W2;
    unsigned short* Wt = (tid < 16384) ? Wt1 : Wt2;
    int i = tid & 16383;
    int k = i >> 7, nn = i & 127;
    Wt[nn * 128 + k] = (unsigned short)f2bf(W[i]);
}

// ---------------- CSR build ----------------

__global__ void hist_kernel(const int* __restrict__ ei, int* __restrict__ deg) {
    int e = blockIdx.x * blockDim.x + threadIdx.x;
    if (e >= EP) return;
    int dst = (e < N_EDGES) ? ei[N_EDGES + e] : (e - N_EDGES);
    atomicAdd(&deg[dst], 1);
}

__global__ __launch_bounds__(256) void scan_a_kernel(const int* __restrict__ deg,
                                                     int* __restrict__ blocksum, int n) {
    __shared__ int ws[4];
    int t = threadIdx.x;
    int base = blockIdx.x * 1024 + t * 4;
    int s = 0;
    #pragma unroll
    for (int j = 0; j < 4; ++j) { int i = base + j; s += (i < n) ? deg[i] : 0; }
    #pragma unroll
    for (int d = 32; d > 0; d >>= 1) s += __shfl_xor(s, d);
    int lane = t & 63, wid = t >> 6;
    if (lane == 0) ws[wid] = s;
    __syncthreads();
    if (t == 0) blocksum[blockIdx.x] = ws[0] + ws[1] + ws[2] + ws[3];
}

// scan_c with inlined block-offset scan (every block redundantly scans the 49 sums)
__global__ __launch_bounds__(256) void scan_c_kernel(const int* __restrict__ deg,
                                                     const int* __restrict__ blocksum,
                                                     int* __restrict__ rowstart, int n) {
    __shared__ int woff[4];
    __shared__ int s_boff;
    int t = threadIdx.x;
    int lane = t & 63, wid = t >> 6;
    if (t < 64) {
        int v = (t < SCAN_BLOCKS) ? blocksum[t] : 0;
        int incl = v;
        #pragma unroll
        for (int d = 1; d < 64; d <<= 1) { int o = __shfl_up(incl, d, 64); if (t >= d) incl += o; }
        if (t == (int)blockIdx.x) s_boff = incl - v;
    }
    if (blockIdx.x == 0 && t == 0) rowstart[n] = EP;
    int base = blockIdx.x * 1024 + t * 4;
    int v[4]; int ls = 0;
    #pragma unroll
    for (int j = 0; j < 4; ++j) { int i = base + j; v[j] = (i < n) ? deg[i] : 0; ls += v[j]; }
    int incl = ls;
    #pragma unroll
    for (int d = 1; d < 64; d <<= 1) { int o = __shfl_up(incl, d, 64); if (lane >= d) incl += o; }
    if (lane == 63) woff[wid] = incl;
    __syncthreads();
    int wpre = 0;
    for (int w = 0; w < wid; ++w) wpre += woff[w];
    int run = s_boff + wpre + (incl - ls);
    #pragma unroll
    for (int j = 0; j < 4; ++j) { int i = base + j; if (i < n) rowstart[i] = run; run += v[j]; }
}

__global__ void fill_kernel(const int* __restrict__ ei, const int* __restrict__ rowstart,
                            int* __restrict__ cursor, int* __restrict__ eids) {
    int e = blockIdx.x * blockDim.x + threadIdx.x;
    if (e >= EP) return;
    int src, dst;
    if (e < N_EDGES) { src = ei[e]; dst = ei[N_EDGES + e]; }
    else             { src = e - N_EDGES; dst = src; }
    int pos = atomicAdd(&cursor[dst], 1);
    eids[rowstart[dst] + pos] = src;
}

// ---------------- fused MFMA GEMM + attention scalars ----------------
// C = A @ W (bf16 out), a_s[n][h] = sum_col C[n][col]*att_s[col] (from f32 accumulators),
// a_d[n][h] = sum_k A[n][k]*weffd[k][h] (from A fragments).
// Layout: lane l = quad*16+lr; A-frag: row m0+lr, k = kb*32+quad*8+j;
//         D: row m0+quad*4+r, col nt*16+lr.

__global__ __launch_bounds__(256) void gemm_fused_f32a_kernel(
    const float* __restrict__ A, const unsigned short* __restrict__ Wt,
    const float* __restrict__ att_s, const float* __restrict__ weffd,
    unsigned short* __restrict__ C, float* __restrict__ a_s, float* __restrict__ a_d, int n) {
    int t = threadIdx.x;
    int l = t & 63;
    int quad = l >> 4, lr = l & 15;
    int m0 = blockIdx.x * 64 + (t >> 6) * 16;
    int arow = m0 + lr; if (arow >= n) arow = n - 1;

    short8 afrag[4];
    float pd0 = 0.f, pd1 = 0.f;
    const float2* wd2 = (const float2*)weffd;
    #pragma unroll
    for (int kb = 0; kb < 4; ++kb) {
        const float4* ap = (const float4*)(A + (size_t)arow * 128 + kb * 32 + quad * 8);
        float4 a0 = ap[0], a1 = ap[1];
        int k0 = kb * 32 + quad * 8;
        float2 w0 = wd2[k0+0], w1 = wd2[k0+1], w2 = wd2[k0+2], w3 = wd2[k0+3];
        float2 w4 = wd2[k0+4], w5 = wd2[k0+5], w6 = wd2[k0+6], w7 = wd2[k0+7];
        pd0 += a0.x*w0.x + a0.y*w1.x + a0.z*w2.x + a0.w*w3.x
             + a1.x*w4.x + a1.y*w5.x + a1.z*w6.x + a1.w*w7.x;
        pd1 += a0.x*w0.y + a0.y*w1.y + a0.z*w2.y + a0.w*w3.y
             + a1.x*w4.y + a1.y*w5.y + a1.z*w6.y + a1.w*w7.y;
        short8 s;
        s[0] = (short)f2bf(a0.x); s[1] = (short)f2bf(a0.y);
        s[2] = (short)f2bf(a0.z); s[3] = (short)f2bf(a0.w);
        s[4] = (short)f2bf(a1.x); s[5] = (short)f2bf(a1.y);
        s[6] = (short)f2bf(a1.z); s[7] = (short)f2bf(a1.w);
        afrag[kb] = s;
    }
    pd0 += __shfl_xor(pd0, 16); pd0 += __shfl_xor(pd0, 32);
    pd1 += __shfl_xor(pd1, 16); pd1 += __shfl_xor(pd1, 32);
    if (l < 16 && m0 + lr < n) *(float2*)(a_d + (size_t)(m0 + lr) * 2) = make_float2(pd0, pd1);

    f32x4 acc[8] = {};
    #pragma unroll
    for (int nt = 0; nt < 8; ++nt) {
        #pragma unroll
        for (int kb = 0; kb < 4; ++kb) {
            short8 b = *(const short8*)(Wt + (size_t)(nt * 16 + lr) * 128 + kb * 32 + quad * 8);
            acc[nt] = __builtin_amdgcn_mfma_f32_16x16x32_bf16(afrag[kb], b, acc[nt], 0, 0, 0);
        }
    }
    // a_s from accumulators
    float asv[8];
    #pragma unroll
    for (int nt = 0; nt < 8; ++nt) asv[nt] = att_s[nt * 16 + lr];
    float pa0[4] = {}, pa1[4] = {};
    #pragma unroll
    for (int nt = 0; nt < 8; ++nt)
        #pragma unroll
        for (int r = 0; r < 4; ++r) {
            if (nt < 4) pa0[r] += acc[nt][r] * asv[nt];
            else        pa1[r] += acc[nt][r] * asv[nt];
        }
    #pragma unroll
    for (int d = 1; d < 16; d <<= 1) {
        #pragma unroll
        for (int r = 0; r < 4; ++r) {
            pa0[r] += __shfl_xor(pa0[r], d);
            pa1[r] += __shfl_xor(pa1[r], d);
        }
    }
    if (lr == 0) {
        #pragma unroll
        for (int r = 0; r < 4; ++r) {
            int row = m0 + quad * 4 + r;
            if (row < n) *(float2*)(a_s + (size_t)row * 2) = make_float2(pa0[r], pa1[r]);
        }
    }
    #pragma unroll
    for (int nt = 0; nt < 8; ++nt)
        #pragma unroll
        for (int r = 0; r < 4; ++r) {
            int row = m0 + quad * 4 + r;
            if (row < n)
                C[(size_t)row * 128 + nt * 16 + lr] = (unsigned short)f2bf(acc[nt][r]);
        }
}

__global__ __launch_bounds__(256) void gemm_fused_bf16_kernel(
    const unsigned short* __restrict__ A, const unsigned short* __restrict__ Wt,
    const float* __restrict__ att_s, const float* __restrict__ weffd,
    unsigned short* __restrict__ C, float* __restrict__ a_s, float* __restrict__ a_d, int n) {
    int t = threadIdx.x;
    int l = t & 63;
    int quad = l >> 4, lr = l & 15;
    int m0 = blockIdx.x * 64 + (t >> 6) * 16;
    int arow = m0 + lr; if (arow >= n) arow = n - 1;

    short8 afrag[4];
    float pd0 = 0.f, pd1 = 0.f;
    const float2* wd2 = (const float2*)weffd;
    #pragma unroll
    for (int kb = 0; kb < 4; ++kb) {
        short8 s = *(const short8*)(A + (size_t)arow * 128 + kb * 32 + quad * 8);
        afrag[kb] = s;
        const unsigned int* u = (const unsigned int*)&s;
        int k0 = kb * 32 + quad * 8;
        #pragma unroll
        for (int d = 0; d < 4; ++d) {
            float x0 = __uint_as_float(u[d] << 16);
            float x1 = __uint_as_float(u[d] & 0xffff0000u);
            float2 wv0 = wd2[k0 + 2*d], wv1 = wd2[k0 + 2*d + 1];
            pd0 += x0 * wv0.x + x1 * wv1.x;
            pd1 += x0 * wv0.y + x1 * wv1.y;
        }
    }
    pd0 += __shfl_xor(pd0, 16); pd0 += __shfl_xor(pd0, 32);
    pd1 += __shfl_xor(pd1, 16); pd1 += __shfl_xor(pd1, 32);
    if (l < 16 && m0 + lr < n) *(float2*)(a_d + (size_t)(m0 + lr) * 2) = make_float2(pd0, pd1);

    f32x4 acc[8] = {};
    #pragma unroll
    for (int nt = 0; nt < 8; ++nt) {
        #pragma unroll
        for (int kb = 0; kb < 4; ++kb) {
            short8 b = *(const short8*)(Wt + (size_t)(nt * 16 + lr) * 128 + kb * 32 + quad * 8);
            acc[nt] = __builtin_amdgcn_mfma_f32_16x16x32_bf16(afrag[kb], b, acc[nt], 0, 0, 0);
        }
    }
    float asv[8];
    #pragma unroll
    for (int nt = 0; nt < 8; ++nt) asv[nt] = att_s[nt * 16 + lr];
    float pa0[4] = {}, pa1[4] = {};
    #pragma unroll
    for (int nt = 0; nt < 8; ++nt)
        #pragma unroll
        for (int r = 0; r < 4; ++r) {
            if (nt < 4) pa0[r] += acc[nt][r] * asv[nt];
            else        pa1[r] += acc[nt][r] * asv[nt];
        }
    #pragma unroll
    for (int d = 1; d < 16; d <<= 1) {
        #pragma unroll
        for (int r = 0; r < 4; ++r) {
            pa0[r] += __shfl_xor(pa0[r], d);
            pa1[r] += __shfl_xor(pa1[r], d);
        }
    }
    if (lr == 0) {
        #pragma unroll
        for (int r = 0; r < 4; ++r) {
            int row = m0 + quad * 4 + r;
            if (row < n) *(float2*)(a_s + (size_t)row * 2) = make_float2(pa0[r], pa1[r]);
        }
    }
    #pragma unroll
    for (int nt = 0; nt < 8; ++nt)
        #pragma unroll
        for (int r = 0; r < 4; ++r) {
            int row = m0 + quad * 4 + r;
            if (row < n)
                C[(size_t)row * 128 + nt * 16 + lr] = (unsigned short)f2bf(acc[nt][r]);
        }
}

// ---------------- edge aggregation: one wave per destination node ----------------
// 32-edge chunks; lanes 0-31 compute head-0 exp, lanes 32-63 head-1; unstabilized softmax.

__global__ __launch_bounds__(256) void aggregate_kernel(
    const int* __restrict__ rowstart, const int* __restrict__ eids,
    const float* __restrict__ a_s, const float* __restrict__ a_d,
    const unsigned int* __restrict__ xs32, const float* __restrict__ bias,
    unsigned int* __restrict__ out32, int n) {
    int wave = (int)((blockIdx.x * blockDim.x + threadIdx.x) >> 6);
    int lane = threadIdx.x & 63;
    if (wave >= n) return;
    int dstn = wave;
    int h    = lane >> 5;
    int j32  = lane & 31;
    int hoff = h << 5;
    int ch   = lane * 2;
    float2 advv = *(const float2*)(a_d + (size_t)dstn * 2);
    float adv = (h == 0) ? advv.x : advv.y;
    int row = rowstart[dstn], end = rowstart[dstn + 1];

    float accA0 = 0.f, accA1 = 0.f, accB0 = 0.f, accB1 = 0.f, lsum = 0.f;
    for (int base = row; base < end; base += 32) {
        int rem = end - base;
        int k = rem < 32 ? rem : 32;
        int idx = base + (j32 < k ? j32 : k - 1);
        int eidv = eids[idx];
        float2 as2 = *(const float2*)(a_s + (size_t)eidv * 2);
        float e = ((h == 0) ? as2.x : as2.y) + adv;
        e = (e > 0.f) ? e : 0.2f * e;
        float pme = (j32 < k) ? __expf(e) : 0.f;
        lsum += pme;
        int jb = 0;
        for (; jb + 4 <= k; jb += 4) {
            #pragma unroll
            for (int u = 0; u < 4; ++u) {
                int j = jb + u;
                int srcn = __shfl(eidv, j);
                float pj = __shfl(pme, j + hoff);
                unsigned int v = xs32[(size_t)srcn * 64 + lane];
                if (u & 1) {
                    accB0 += pj * __uint_as_float(v << 16);
                    accB1 += pj * __uint_as_float(v & 0xffff0000u);
                } else {
                    accA0 += pj * __uint_as_float(v << 16);
                    accA1 += pj * __uint_as_float(v & 0xffff0000u);
                }
            }
        }
        for (; jb < k; ++jb) {
            int srcn = __shfl(eidv, jb);
            float pj = __shfl(pme, jb + hoff);
            unsigned int v = xs32[(size_t)srcn * 64 + lane];
            accA0 += pj * __uint_as_float(v << 16);
            accA1 += pj * __uint_as_float(v & 0xffff0000u);
        }
    }
    // per-half denominator (head h lives in half h)
    #pragma unroll
    for (int d = 1; d <= 16; d <<= 1) lsum += __shfl_xor(lsum, d);
    float inv = 1.f / lsum;
    float o0 = fmaxf((accA0 + accB0) * inv + bias[ch], 0.f);
    float o1 = fmaxf((accA1 + accB1) * inv + bias[ch + 1], 0.f);
    out32[(size_t)dstn * 64 + lane] = f2bf(o0) | (f2bf(o1) << 16);
}

// ---------------- pool: partial sums + tiny final linear ----------------

#define POOL_CHUNK 128

__global__ __launch_bounds__(256) void pool_partial_kernel(
    const unsigned short* __restrict__ Hf, const int* __restrict__ batch,
    float* __restrict__ sums, int n) {
    int t = threadIdx.x;
    int c = t & 127, half = t >> 7;
    int start = blockIdx.x * POOL_CHUNK;
    int end = min(start + POOL_CHUNK, n);
    float acc = 0.f;
    int cur = -1;
    for (int i = start + half; i < end; i += 2) {
        int g = batch[i];
        if (g != cur) {
            if (cur >= 0) atomicAdd(&sums[cur * 128 + c], acc);
            acc = 0.f; cur = g;
        }
        acc += bf2f(Hf[(size_t)i * 128 + c]);
    }
    if (cur >= 0) atomicAdd(&sums[cur * 128 + c], acc);
}

__global__ void final_linear_kernel(const float* __restrict__ sums,
                                    const int* __restrict__ batch,
                                    const float* __restrict__ Wl, const float* __restrict__ bl,
                                    float* __restrict__ out, int n) {
    int t = blockIdx.x * blockDim.x + threadIdx.x;
    if (t >= N_GRAPHS * OUT_DIM) return;
    int g = t / OUT_DIM, o = t % OUT_DIM;
    int lo = 0, hi = n;
    while (lo < hi) { int mid = (lo + hi) >> 1; if (batch[mid] < g) lo = mid + 1; else hi = mid; }
    int s0 = lo; hi = n;
    while (lo < hi) { int mid = (lo + hi) >> 1; if (batch[mid] < g + 1) lo = mid + 1; else hi = mid; }
    float cnt = (float)(lo - s0);
    float inv = 1.f / fmaxf(cnt, 1.f);
    float s = bl[o];
    for (int c = 0; c < 128; ++c) s += sums[g * 128 + c] * inv * Wl[c * OUT_DIM + o];
    out[g * OUT_DIM + o] = s;
}

// ---------------- launch ----------------

extern "C" void kernel_launch(void* const* d_in, const int* in_sizes, int n_in,
                              void* d_out, int out_size, void* d_ws, size_t ws_size,
                              hipStream_t stream) {
    const float* x    = (const float*)d_in[0];
    const int*   ei   = (const int*)d_in[1];
    const int*   batch= (const int*)d_in[2];
    const float* Ws1  = (const float*)d_in[3];
    const float* Wd1  = (const float*)d_in[4];
    const float* as1  = (const float*)d_in[5];
    const float* ad1  = (const float*)d_in[6];
    const float* b1   = (const float*)d_in[7];
    const float* Ws2  = (const float*)d_in[8];
    const float* Wd2  = (const float*)d_in[9];
    const float* as2  = (const float*)d_in[10];
    const float* ad2  = (const float*)d_in[11];
    const float* b2   = (const float*)d_in[12];
    const float* Wl   = (const float*)d_in[13];
    const float* bl   = (const float*)d_in[14];
    float* out = (float*)d_out;

    char* p = (char*)d_ws;
    auto alloc = [&](size_t bytes) {
        void* r = (void*)p;
        p += (bytes + 255) & ~(size_t)255;
        return r;
    };
    int* degcur   = (int*)alloc(sizeof(int) * N_NODES * 2);   // deg+cursor contiguous
    int* deg      = degcur;
    int* cursor   = degcur + N_NODES;
    int* rowstart = (int*)alloc(sizeof(int) * (N_NODES + 1));
    int* eids     = (int*)alloc(sizeof(int) * EP);
    int* bsum     = (int*)alloc(sizeof(int) * 64);
    float* a_s    = (float*)alloc(sizeof(float) * N_NODES * 2);
    float* a_d    = (float*)alloc(sizeof(float) * N_NODES * 2);
    float* sums   = (float*)alloc(sizeof(float) * N_GRAPHS * 128);
    float* weffd1 = (float*)alloc(sizeof(float) * 128 * 2);
    float* weffd2 = (float*)alloc(sizeof(float) * 128 * 2);
    unsigned short* Wt1  = (unsigned short*)alloc(sizeof(short) * 128 * 128);
    unsigned short* Wt2  = (unsigned short*)alloc(sizeof(short) * 128 * 128);
    unsigned short* bufA = (unsigned short*)alloc(sizeof(short) * (size_t)N_NODES * F_DIM); // xs
    unsigned short* bufB = (unsigned short*)alloc(sizeof(short) * (size_t)N_NODES * F_DIM); // h

    // ---- prep + CSR build ----
    prep_kernel<<<128, 256, 0, stream>>>(Ws1, Ws2, Wd1, ad1, Wd2, ad2,
                                         Wt1, Wt2, weffd1, weffd2,
                                         (uint4*)degcur, (uint4*)sums);
    hist_kernel<<<(EP + 255) / 256, 256, 0, stream>>>(ei, deg);
    scan_a_kernel<<<SCAN_BLOCKS, 256, 0, stream>>>(deg, bsum, N_NODES);
    scan_c_kernel<<<SCAN_BLOCKS, 256, 0, stream>>>(deg, bsum, rowstart, N_NODES);
    fill_kernel<<<(EP + 255) / 256, 256, 0, stream>>>(ei, rowstart, cursor, eids);

    const int gemm_grid = (N_NODES + 63) / 64;
    const int agg_grid  = (N_NODES + 3) / 4;

    // ---- layer 1 ----
    gemm_fused_f32a_kernel<<<gemm_grid, 256, 0, stream>>>(x, Wt1, as1, weffd1,
                                                          bufA, a_s, a_d, N_NODES);
    aggregate_kernel<<<agg_grid, 256, 0, stream>>>(rowstart, eids, a_s, a_d,
                                                   (const unsigned int*)bufA, b1,
                                                   (unsigned int*)bufB, N_NODES);

    // ---- layer 2 ----
    gemm_fused_bf16_kernel<<<gemm_grid, 256, 0, stream>>>(bufB, Wt2, as2, weffd2,
                                                          bufA, a_s, a_d, N_NODES);
    aggregate_kernel<<<agg_grid, 256, 0, stream>>>(rowstart, eids, a_s, a_d,
                                                   (const unsigned int*)bufA, b2,
                                                   (unsigned int*)bufB, N_NODES);

    // ---- pool + linear ----
    pool_partial_kernel<<<(N_NODES + POOL_CHUNK - 1) / POOL_CHUNK, 256, 0, stream>>>(bufB, batch, sums, N_NODES);
    final_linear_kernel<<<(N_GRAPHS * OUT_DIM + 255) / 256, 256, 0, stream>>>(sums, batch, Wl, bl, out, N_NODES);
}